// Round 2
// baseline (598.921 us; speedup 1.0000x reference)
//
#include <hip/hip_runtime.h>

#define NN 4096
#define NFEAT 512
#define NHID 64
#define H1 8
#define NCLS 16
#define BND 40.0f   // static upper bound for nbmax (true ~13 layer1, ~0.5 layer2)
#define VSTR 40     // bf16 elems per vT row: 32 j + 8 pad = 80B rows, 16B-aligned

typedef short bf16x8 __attribute__((ext_vector_type(8)));
typedef float f32x4 __attribute__((ext_vector_type(4)));

__device__ __forceinline__ unsigned short f2bf(float f) {
    unsigned u = __float_as_uint(f);
    u += 0x7fffu + ((u >> 16) & 1u);          // RNE
    return (unsigned short)(u >> 16);
}
__device__ __forceinline__ float leaky(float v) { return fmaxf(v, 0.2f * v); }
// pack two fp32 -> dword of two bf16 (round-half-up, 3 instr per 2 values)
__device__ __forceinline__ unsigned pkbf(float lo, float hi) {
    return __builtin_amdgcn_perm(__float_as_uint(hi) + 0x8000u,
                                 __float_as_uint(lo) + 0x8000u, 0x07060302u);
}
__device__ __forceinline__ bf16x8 mk8(unsigned a, unsigned b, unsigned c, unsigned d) {
    union { unsigned u[4]; bf16x8 v; } cv;
    cv.u[0] = a; cv.u[1] = b; cv.u[2] = c; cv.u[3] = d; return cv.v;
}
// bit i of b -> 0x00000000 / 0xFFFFFFFF in 1-2 VALU (v_bfe_i32 width=1)
__device__ __forceinline__ unsigned bmask(unsigned b, int i) {
#if __has_builtin(__builtin_amdgcn_sbfe)
    return (unsigned)__builtin_amdgcn_sbfe((int)b, (unsigned)i, 1u);
#else
    return 0u - ((b >> i) & 1u);
#endif
}

// ---------------------------------------------------------------------------
// Dual-role: bx < 4096 -> pack adj row; else -> W1 -> MFMA-frag-major bf16.
// w1f element ((h*16+kg)*4+nt)*512 + lane*8 + e  =  W1[h][kg*32+q*8+e][nt*16+n]
// with lane = q*16+n. Consumer B-loads are then lane-contiguous (coalesced).
// ---------------------------------------------------------------------------
__global__ __launch_bounds__(256)
void k_prep(const int* __restrict__ adj, unsigned long long* __restrict__ bits,
            const float* __restrict__ W1, unsigned short* __restrict__ w1f)
{
    __shared__ float wt[64][65];
    const int t = threadIdx.x, bx = blockIdx.x;
    if (bx < NN) {
        const int wv = t >> 6, lane = t & 63;
        const int* ap = adj + (size_t)bx * NN;
        for (int w = wv; w < 64; w += 4) {
            unsigned long long m = __ballot(ap[w * 64 + lane] > 0);
            if (lane == 0) bits[(size_t)bx * 64 + w] = m;
        }
        return;
    }
    const int kt = (bx - NN) & 7, h = (bx - NN) >> 3;
    #pragma unroll
    for (int i = 0; i < 4; ++i) {
        const int f = t + 256 * i;
        const int r = f >> 4, c4 = f & 15;   // r = k_local, c4*4 = c
        const float4 v = *(const float4*)(W1 + ((size_t)(h * NFEAT) + kt * 64 + r) * NHID + c4 * 4);
        wt[r][c4 * 4 + 0] = v.x; wt[r][c4 * 4 + 1] = v.y;
        wt[r][c4 * 4 + 2] = v.z; wt[r][c4 * 4 + 3] = v.w;
    }
    __syncthreads();
    #pragma unroll
    for (int s = 0; s < 2; ++s) {
        const int o = t + s * 256;                   // octet id 0..511
        const int kg2 = o >> 8, rem = o & 255;
        const int nt = rem >> 6, lane2 = rem & 63;
        const int qq = lane2 >> 4, nn = lane2 & 15;
        const int kl = kg2 * 32 + qq * 8;            // k_local base
        const int c = nt * 16 + nn;
        uint4 w;
        w.x = pkbf(wt[kl + 0][c], wt[kl + 1][c]);
        w.y = pkbf(wt[kl + 2][c], wt[kl + 3][c]);
        w.z = pkbf(wt[kl + 4][c], wt[kl + 5][c]);
        w.w = pkbf(wt[kl + 6][c], wt[kl + 7][c]);
        *(uint4*)(w1f + (((size_t)h * 16 + kt * 2 + kg2) * 4 + nt) * 512 + lane2 * 8) = w;
    }
}

// ---------------------------------------------------------------------------
// feats1 = x @ W1 via MFMA (x cast in-register, W1 frag-major) -> f1bT +
// s1 + F1a/F2a. grid (64,8), 256 thr.
// ---------------------------------------------------------------------------
__global__ __launch_bounds__(256)
void k_feats1(const float* __restrict__ x, const unsigned short* __restrict__ w1f,
              const float* __restrict__ as1, const float* __restrict__ an1,
              unsigned short* __restrict__ f1bT, float* __restrict__ s1,
              float* __restrict__ F1a, float* __restrict__ F2a)
{
    const int t = threadIdx.x, wv = t >> 6, lane = t & 63;
    const int q = lane >> 4, n = lane & 15;
    const int h = blockIdx.y, R0 = blockIdx.x * 64;
    const int row = R0 + wv * 16 + n;
    const float* ap = x + (size_t)row * NFEAT;
    const unsigned short* wp = w1f + (size_t)h * 16 * 4 * 512 + lane * 8;
    f32x4 acc[4] = {{0.f,0.f,0.f,0.f},{0.f,0.f,0.f,0.f},{0.f,0.f,0.f,0.f},{0.f,0.f,0.f,0.f}};
    #pragma unroll 4
    for (int kg = 0; kg < 16; ++kg) {
        const float4 xa = *(const float4*)(ap + kg * 32 + q * 8);
        const float4 xb = *(const float4*)(ap + kg * 32 + q * 8 + 4);
        const bf16x8 af = mk8(pkbf(xa.x, xa.y), pkbf(xa.z, xa.w),
                              pkbf(xb.x, xb.y), pkbf(xb.z, xb.w));
        #pragma unroll
        for (int nt = 0; nt < 4; ++nt) {
            const bf16x8 bf = *(const bf16x8*)(wp + (size_t)(kg * 4 + nt) * 512);
            acc[nt] = __builtin_amdgcn_mfma_f32_16x16x32_bf16(af, bf, acc[nt], 0, 0, 0);
        }
    }
    #pragma unroll
    for (int nt = 0; nt < 4; ++nt) {
        uint2 w;
        w.x = pkbf(acc[nt][0], acc[nt][1]);
        w.y = pkbf(acc[nt][2], acc[nt][3]);
        *(uint2*)(f1bT + ((size_t)h * NHID + nt * 16 + n) * NN + R0 + wv * 16 + q * 4) = w;
    }
    float asv[4], anv[4];
    #pragma unroll
    for (int nt = 0; nt < 4; ++nt) {
        asv[nt] = as1[h * NHID + nt * 16 + n];
        anv[nt] = an1[h * NHID + nt * 16 + n];
    }
    #pragma unroll
    for (int i = 0; i < 4; ++i) {
        float ps = acc[0][i]*asv[0] + acc[1][i]*asv[1] + acc[2][i]*asv[2] + acc[3][i]*asv[3];
        float pn = acc[0][i]*anv[0] + acc[1][i]*anv[1] + acc[2][i]*anv[2] + acc[3][i]*anv[3];
        #pragma unroll
        for (int off = 8; off > 0; off >>= 1) {
            ps += __shfl_xor(ps, off, 64);
            pn += __shfl_xor(pn, off, 64);
        }
        if (n == 0) {
            const int idx = R0 + wv * 16 + q * 4 + i;
            s1[h * NN + idx] = ps;
            F1a[h * NN + idx] = __expf(pn - BND);
            F2a[h * NN + idx] = __expf(0.2f * (pn - BND));
        }
    }
}

// ---------------------------------------------------------------------------
// Layer-1 aggregation. 1024 thr = 16 waves = (rg = wv>>3) row-group of 32 x
// (jq = wv&7) j-eighth (512 j). Block = 64 rows x full j (block-level B-panel
// reuse keeps HBM at ~22 MB -- R1 showed removing it -> 684 MB HBM thrash).
// 8 LDS j-streams, 32-j double-buffered tiles (VSTR=40 -> 81920 B total),
// 1 barrier/iter, 16 iters. 2 blocks/CU x 16 waves = 32 waves/CU (vs 16
// before) to fill the 4-cyc-latency VALU chains. VGPR capped at 64 via
// __launch_bounds__(1024,8). Two-pass fused softmax epilogue in same LDS.
// ---------------------------------------------------------------------------
__global__ __launch_bounds__(1024, 8)
void k_gat1(const unsigned short* __restrict__ f1bT, const float* __restrict__ s1,
            const float* __restrict__ F1, const float* __restrict__ F2,
            const unsigned long long* __restrict__ abits, const float* __restrict__ b1,
            unsigned short* __restrict__ hcatb)
{
    __shared__ __align__(16) char smem[8 * 2 * 64 * VSTR * 2];   // 81920 B
    unsigned short* vT = (unsigned short*)smem;                  // [jq*2+db][64][VSTR]

    const int t = threadIdx.x, wv = t >> 6, lane = t & 63;
    const int q = lane >> 4, n = lane & 15;
    const int rg = wv >> 3, jq = wv & 7;
    const int h = blockIdx.y, R0 = blockIdx.x * 64;
    const int rowA = R0 + rg * 32 + n;
    const int rowB = rowA + 16;
    const float vA = s1[h * NN + rowA] + BND, mhA = leaky(vA);
    const float vB = s1[h * NN + rowB] + BND, mhB = leaky(vB);
    const float E1A = __expf(vA - mhA), E2A = __expf(0.2f * vA - mhA);
    const float E1B = __expf(vB - mhB), E2B = __expf(0.2f * vB - mhB);
    const unsigned* arowA32 = (const unsigned*)abits + (size_t)rowA * 128 + jq * 16;
    const unsigned* arowB32 = (const unsigned*)abits + (size_t)rowB * 128 + jq * 16;
    const float* F1p = F1 + (size_t)h * NN + jq * 512;
    const float* F2p = F2 + (size_t)h * NN + jq * 512;

    // staging: thread t stages stream (t>>7); cols sc0, sc0+32; j-octet sj8.
    // 4 consecutive threads cover 64B contiguous j -> coalesced cache lines.
    const int stile = t >> 7;
    const int sc0 = (t & 127) >> 2, sj8 = t & 3;
    const unsigned short* sbase = f1bT + (size_t)h * NHID * NN + (size_t)sc0 * NN
                                + stile * 512 + sj8 * 8;
    const int dof = sc0 * VSTR + sj8 * 8;

    f32x4 accA[4] = {{0.f,0.f,0.f,0.f},{0.f,0.f,0.f,0.f},{0.f,0.f,0.f,0.f},{0.f,0.f,0.f,0.f}};
    f32x4 accB[4] = {{0.f,0.f,0.f,0.f},{0.f,0.f,0.f,0.f},{0.f,0.f,0.f,0.f},{0.f,0.f,0.f,0.f}};
    float lsA = 0.f, lsB = 0.f;

    {   // preload it=0 into db=0 for this thread's stream tile
        int4 v0 = *(const int4*)(sbase);
        int4 v1 = *(const int4*)(sbase + (size_t)32 * NN);
        unsigned short* d = vT + (stile * 2 + 0) * (64 * VSTR) + dof;
        *(int4*)(d) = v0;
        *(int4*)(d + 32 * VSTR) = v1;
    }
    __syncthreads();

    #pragma unroll 2
    for (int it = 0; it < 16; ++it) {
        const int db = it & 1;
        int4 p0, p1;
        if (it < 15) {
            const int js = (it + 1) * 32;
            p0 = *(const int4*)(sbase + js);
            p1 = *(const int4*)(sbase + (size_t)32 * NN + js);
        }
        const int j0 = it * 32;
        const int kb = q * 8;
        const unsigned aA = arowA32[it], aB = arowB32[it];
        const float4 f1a = *(const float4*)(F1p + j0 + kb);
        const float4 f1b = *(const float4*)(F1p + j0 + kb + 4);
        const float4 f2a = *(const float4*)(F2p + j0 + kb);
        const float4 f2b = *(const float4*)(F2p + j0 + kb + 4);
        const float F1v[8] = {f1a.x, f1a.y, f1a.z, f1a.w, f1b.x, f1b.y, f1b.z, f1b.w};
        const float F2v[8] = {f2a.x, f2a.y, f2a.z, f2a.w, f2b.x, f2b.y, f2b.z, f2b.w};
        const unsigned bA8 = (aA >> kb) & 0xffu;
        const unsigned bB8 = (aB >> kb) & 0xffu;
        unsigned uA[4], uB[4];
        #pragma unroll
        for (int jp = 0; jp < 4; ++jp) {
            float a0 = fmaxf(E1A * F1v[2*jp],   E2A * F2v[2*jp]);
            float a1 = fmaxf(E1A * F1v[2*jp+1], E2A * F2v[2*jp+1]);
            a0 = __uint_as_float(__float_as_uint(a0) & bmask(bA8, 2*jp));
            a1 = __uint_as_float(__float_as_uint(a1) & bmask(bA8, 2*jp+1));
            lsA += a0 + a1;
            uA[jp] = pkbf(a0, a1);
            float b0  = fmaxf(E1B * F1v[2*jp],   E2B * F2v[2*jp]);
            float b1v = fmaxf(E1B * F1v[2*jp+1], E2B * F2v[2*jp+1]);
            b0  = __uint_as_float(__float_as_uint(b0)  & bmask(bB8, 2*jp));
            b1v = __uint_as_float(__float_as_uint(b1v) & bmask(bB8, 2*jp+1));
            lsB += b0 + b1v;
            uB[jp] = pkbf(b0, b1v);
        }
        const bf16x8 afA = mk8(uA[0], uA[1], uA[2], uA[3]);
        const bf16x8 afB = mk8(uB[0], uB[1], uB[2], uB[3]);
        const unsigned short* tbase = vT + (jq * 2 + db) * (64 * VSTR);
        #pragma unroll
        for (int nt = 0; nt < 4; ++nt) {
            const bf16x8 bf = *(const bf16x8*)(tbase + (nt * 16 + n) * VSTR + kb);
            accA[nt] = __builtin_amdgcn_mfma_f32_16x16x32_bf16(afA, bf, accA[nt], 0, 0, 0);
            accB[nt] = __builtin_amdgcn_mfma_f32_16x16x32_bf16(afB, bf, accB[nt], 0, 0, 0);
        }
        if (it < 15) {
            unsigned short* d = vT + (stile * 2 + (db ^ 1)) * (64 * VSTR) + dof;
            *(int4*)(d) = p0;
            *(int4*)(d + 32 * VSTR) = p1;
        }
        __syncthreads();
    }

    lsA += __shfl_xor(lsA, 16, 64); lsA += __shfl_xor(lsA, 32, 64);
    lsB += __shfl_xor(lsB, 16, 64); lsB += __shfl_xor(lsB, 32, 64);

    // epilogue: reuse smem. cmbf [8 jq][32 lrows][68] + lwf [8][32] = 70656 B
    float (*cmbf)[32][68] = (float (*)[32][68])smem;
    float (*lwf)[32] = (float (*)[32])(smem + 8 * 32 * 68 * 4);

    // ---- pass A: accA -> local rows {rg*16 + 0..15} <-> global rg*32 + 0..15
    #pragma unroll
    for (int nt = 0; nt < 4; ++nt)
        #pragma unroll
        for (int i = 0; i < 4; ++i)
            cmbf[jq][rg * 16 + q * 4 + i][nt * 16 + n] = accA[nt][i];
    if (q == 0) lwf[jq][rg * 16 + n] = lsA;
    __syncthreads();
    {
        const int lr = t >> 5, c0 = (t & 31) * 2;
        float t0 = 0.f, t1 = 0.f, lt = 0.f;
        #pragma unroll
        for (int jj = 0; jj < 8; ++jj) {
            const float2 v = *(const float2*)&cmbf[jj][lr][c0];
            t0 += v.x; t1 += v.y;
            lt += lwf[jj][lr];
        }
        const float o0 = fmaxf(t0 / lt + b1[h * NHID + c0], 0.f);     // relu; elu(x>=0)=x
        const float o1 = fmaxf(t1 / lt + b1[h * NHID + c0 + 1], 0.f);
        const int grow = R0 + (lr >> 4) * 32 + (lr & 15);
        *(unsigned*)(hcatb + (size_t)grow * (H1 * NHID) + h * NHID + c0) = pkbf(o0, o1);
    }
    __syncthreads();

    // ---- pass B: accB -> local rows <-> global rg*32 + 16 + 0..15
    #pragma unroll
    for (int nt = 0; nt < 4; ++nt)
        #pragma unroll
        for (int i = 0; i < 4; ++i)
            cmbf[jq][rg * 16 + q * 4 + i][nt * 16 + n] = accB[nt][i];
    if (q == 0) lwf[jq][rg * 16 + n] = lsB;
    __syncthreads();
    {
        const int lr = t >> 5, c0 = (t & 31) * 2;
        float t0 = 0.f, t1 = 0.f, lt = 0.f;
        #pragma unroll
        for (int jj = 0; jj < 8; ++jj) {
            const float2 v = *(const float2*)&cmbf[jj][lr][c0];
            t0 += v.x; t1 += v.y;
            lt += lwf[jj][lr];
        }
        const float o0 = fmaxf(t0 / lt + b1[h * NHID + c0], 0.f);
        const float o1 = fmaxf(t1 / lt + b1[h * NHID + c0 + 1], 0.f);
        const int grow = R0 + (lr >> 4) * 32 + 16 + (lr & 15);
        *(unsigned*)(hcatb + (size_t)grow * (H1 * NHID) + h * NHID + c0) = pkbf(o0, o1);
    }
}

// ---------------------------------------------------------------------------
// feats2 = hcatb @ W2 (W2 -> bf16 LDS transpose in-kernel) -> f2bT + s2 +
// F1b/F2b. grid 128, 128 thr.
// ---------------------------------------------------------------------------
__global__ __launch_bounds__(128)
void k_feats2(const unsigned short* __restrict__ hcatb, const float* __restrict__ W2,
              const float* __restrict__ as2, const float* __restrict__ an2,
              unsigned short* __restrict__ f2bT, float* __restrict__ s2,
              float* __restrict__ F1b, float* __restrict__ F2b)
{
    __shared__ __align__(16) unsigned short w2T[NCLS][520];
    const int t = threadIdx.x, wv = t >> 6, lane = t & 63;
    const int q = lane >> 4, n = lane & 15;
    #pragma unroll
    for (int i = 0; i < 16; ++i) {
        const int f4 = t + 128 * i;
        const float4 v = ((const float4*)W2)[f4];
        const int k = f4 >> 2, c0 = (f4 & 3) * 4;
        w2T[c0 + 0][k] = f2bf(v.x); w2T[c0 + 1][k] = f2bf(v.y);
        w2T[c0 + 2][k] = f2bf(v.z); w2T[c0 + 3][k] = f2bf(v.w);
    }
    __syncthreads();

    const int R0 = blockIdx.x * 32;
    const int row = R0 + wv * 16 + n;
    const unsigned short* ap = hcatb + (size_t)row * NFEAT;
    f32x4 acc = {0.f, 0.f, 0.f, 0.f};
    #pragma unroll 4
    for (int k0 = 0; k0 < NFEAT; k0 += 32) {
        const bf16x8 af = *(const bf16x8*)(ap + k0 + q * 8);
        const bf16x8 bf = *(const bf16x8*)&w2T[n][k0 + q * 8];
        acc = __builtin_amdgcn_mfma_f32_16x16x32_bf16(af, bf, acc, 0, 0, 0);
    }
    uint2 w;
    w.x = pkbf(acc[0], acc[1]);
    w.y = pkbf(acc[2], acc[3]);
    *(uint2*)(f2bT + (size_t)n * NN + R0 + wv * 16 + q * 4) = w;
    const float asv = as2[n], anv = an2[n];
    #pragma unroll
    for (int i = 0; i < 4; ++i) {
        float ps = acc[i] * asv, pn = acc[i] * anv;
        #pragma unroll
        for (int off = 8; off > 0; off >>= 1) {
            ps += __shfl_xor(ps, off, 64);
            pn += __shfl_xor(pn, off, 64);
        }
        if (n == 0) {
            const int idx = R0 + wv * 16 + q * 4 + i;
            s2[idx] = ps;
            F1b[idx] = __expf(pn - BND);
            F2b[idx] = __expf(0.2f * (pn - BND));
        }
    }
}

// ---------------------------------------------------------------------------
// Layer-2 aggregation + relu + log_softmax. 1024 thr = 16 wave j-sixteenths.
// ---------------------------------------------------------------------------
__global__ __launch_bounds__(1024)
void k_gat2(const unsigned short* __restrict__ f2bT, const float* __restrict__ s2,
            const float* __restrict__ F1, const float* __restrict__ F2,
            const unsigned long long* __restrict__ abits, const float* __restrict__ b2,
            float* __restrict__ out)
{
    __shared__ float cmb[16][16][17];
    __shared__ float lw[16][16];
    const int t = threadIdx.x, wv = t >> 6, lane = t & 63;
    const int q = lane >> 4, n = lane & 15;
    const int R0 = blockIdx.x * 16, row = R0 + n;
    const float v = s2[row] + BND, mhat = leaky(v);
    const float E1 = __expf(v - mhat), E2 = __expf(0.2f * v - mhat);
    const unsigned long long* arow = abits + (size_t)row * 64;

    f32x4 acc = {0.f, 0.f, 0.f, 0.f};
    float lsum = 0.f;
    const int jbeg = wv * 256;
    for (int j0 = jbeg; j0 < jbeg + 256; j0 += 64) {
        const unsigned long long a64 = arow[j0 >> 6];
        #pragma unroll
        for (int ch = 0; ch < 2; ++ch) {
            const int kb = ch * 32 + q * 8;
            const float4 f1a = *(const float4*)(F1 + j0 + kb);
            const float4 f1b = *(const float4*)(F1 + j0 + kb + 4);
            const float4 f2a = *(const float4*)(F2 + j0 + kb);
            const float4 f2b = *(const float4*)(F2 + j0 + kb + 4);
            const float F1v[8] = {f1a.x, f1a.y, f1a.z, f1a.w, f1b.x, f1b.y, f1b.z, f1b.w};
            const float F2v[8] = {f2a.x, f2a.y, f2a.z, f2a.w, f2b.x, f2b.y, f2b.z, f2b.w};
            const unsigned b8 = (unsigned)(a64 >> kb) & 0xffu;
            unsigned au[4];
            #pragma unroll
            for (int jp = 0; jp < 4; ++jp) {
                float p0 = fmaxf(E1 * F1v[2*jp],   E2 * F2v[2*jp]);
                float p1 = fmaxf(E1 * F1v[2*jp+1], E2 * F2v[2*jp+1]);
                p0 = __uint_as_float(__float_as_uint(p0) & bmask(b8, 2*jp));
                p1 = __uint_as_float(__float_as_uint(p1) & bmask(b8, 2*jp+1));
                lsum += p0 + p1;
                au[jp] = pkbf(p0, p1);
            }
            const bf16x8 af = mk8(au[0], au[1], au[2], au[3]);
            const bf16x8 bf = *(const bf16x8*)(f2bT + (size_t)n * NN + j0 + kb);
            acc = __builtin_amdgcn_mfma_f32_16x16x32_bf16(af, bf, acc, 0, 0, 0);
        }
    }
    lsum += __shfl_xor(lsum, 16, 64);
    lsum += __shfl_xor(lsum, 32, 64);
    #pragma unroll
    for (int i = 0; i < 4; ++i) cmb[wv][q * 4 + i][n] = acc[i];
    if (q == 0) lw[wv][n] = lsum;
    __syncthreads();

    if (t < 256) {
        const int r = t >> 4, c = t & 15;
        float tot = 0.f, lt = 0.f;
        #pragma unroll
        for (int w16 = 0; w16 < 16; ++w16) { tot += cmb[w16][r][c]; lt += lw[w16][r]; }
        float val = fmaxf(tot / lt + b2[c], 0.f);
        float mx = val;
        #pragma unroll
        for (int off = 1; off < 16; off <<= 1) mx = fmaxf(mx, __shfl_xor(mx, off, 64));
        const float e = __expf(val - mx);
        float se = e;
        #pragma unroll
        for (int off = 1; off < 16; off <<= 1) se += __shfl_xor(se, off, 64);
        out[(size_t)(R0 + r) * NCLS + c] = val - mx - __logf(se);
    }
}

// ---------------------------------------------------------------------------
extern "C" void kernel_launch(void* const* d_in, const int* in_sizes, int n_in,
                              void* d_out, int out_size, void* d_ws, size_t ws_size,
                              hipStream_t stream)
{
    const float* x   = (const float*)d_in[0];
    const int*   adj = (const int*)  d_in[1];
    const float* W1  = (const float*)d_in[2];
    const float* b1  = (const float*)d_in[3];
    const float* as1 = (const float*)d_in[4];
    const float* an1 = (const float*)d_in[5];
    const float* W2  = (const float*)d_in[6];
    const float* b2  = (const float*)d_in[7];
    const float* as2 = (const float*)d_in[8];
    const float* an2 = (const float*)d_in[9];
    float* out = (float*)d_out;

    char* ws = (char*)d_ws;
    unsigned long long* abits = (unsigned long long*)(ws);            // 2 MB
    unsigned short* f1bT  = (unsigned short*)(ws + (2u << 20));       // 4 MB
    unsigned short* hcatb = (unsigned short*)(ws + (6u << 20));       // 4 MB
    unsigned short* w1f   = (unsigned short*)(ws + (10u << 20));      // 512 KB
    char* ws2 = ws + (10u << 20) + (512u << 10);
    float* s1   = (float*)(ws2);                                      // 128 KB
    float* F1a  = (float*)(ws2 + (128u << 10));                       // 128 KB
    float* F2a  = (float*)(ws2 + (256u << 10));                       // 128 KB
    unsigned short* f2bT = (unsigned short*)(ws2 + (384u << 10));     // 128 KB
    float* s2   = (float*)(ws2 + (512u << 10));                       // 16 KB
    float* F1b  = (float*)(ws2 + (528u << 10));                       // 16 KB
    float* F2b  = (float*)(ws2 + (544u << 10));                       // 16 KB

    k_prep  <<<dim3(NN + 64),     256, 0, stream>>>(adj, abits, W1, w1f);
    k_feats1<<<dim3(NN / 64, H1), 256, 0, stream>>>(x, w1f, as1, an1, f1bT, s1, F1a, F2a);
    k_gat1  <<<dim3(NN / 64, H1), 1024, 0, stream>>>(f1bT, s1, F1a, F2a, abits, b1, hcatb);
    k_feats2<<<dim3(NN / 32),     128, 0, stream>>>(hcatb, W2, as2, an2, f2bT, s2, F1b, F2b);
    k_gat2  <<<dim3(NN / 16),     1024, 0, stream>>>(f2bT, s2, F1b, F2b, abits, b2, out);
}

// Round 4
// 357.358 us; speedup vs baseline: 1.6760x; 1.6760x over previous
//
#include <hip/hip_runtime.h>

#define NN 4096
#define NFEAT 512
#define NHID 64
#define H1 8
#define NCLS 16
#define BND 40.0f   // static upper bound for nbmax (true ~13 layer1, ~0.5 layer2)
#define VSTR 40     // bf16 elems per vT row: 32 j + 8 pad = 80B rows, 16B-aligned

typedef short bf16x8 __attribute__((ext_vector_type(8)));
typedef float f32x4 __attribute__((ext_vector_type(4)));

__device__ __forceinline__ unsigned short f2bf(float f) {
    unsigned u = __float_as_uint(f);
    u += 0x7fffu + ((u >> 16) & 1u);          // RNE
    return (unsigned short)(u >> 16);
}
__device__ __forceinline__ float leaky(float v) { return fmaxf(v, 0.2f * v); }
// pack two fp32 -> dword of two bf16 (round-half-up, 3 instr per 2 values)
__device__ __forceinline__ unsigned pkbf(float lo, float hi) {
    return __builtin_amdgcn_perm(__float_as_uint(hi) + 0x8000u,
                                 __float_as_uint(lo) + 0x8000u, 0x07060302u);
}
__device__ __forceinline__ bf16x8 mk8(unsigned a, unsigned b, unsigned c, unsigned d) {
    union { unsigned u[4]; bf16x8 v; } cv;
    cv.u[0] = a; cv.u[1] = b; cv.u[2] = c; cv.u[3] = d; return cv.v;
}
// bit i of b -> 0x00000000 / 0xFFFFFFFF in 1-2 VALU (v_bfe_i32 width=1)
__device__ __forceinline__ unsigned bmask(unsigned b, int i) {
#if __has_builtin(__builtin_amdgcn_sbfe)
    return (unsigned)__builtin_amdgcn_sbfe((int)b, (unsigned)i, 1u);
#else
    return 0u - ((b >> i) & 1u);
#endif
}

// ---------------------------------------------------------------------------
// Dual-role: bx < 4096 -> pack adj row; else -> W1 -> MFMA-frag-major bf16.
// w1f element ((h*16+kg)*4+nt)*512 + lane*8 + e  =  W1[h][kg*32+q*8+e][nt*16+n]
// with lane = q*16+n. Consumer B-loads are then lane-contiguous (coalesced).
// ---------------------------------------------------------------------------
__global__ __launch_bounds__(256)
void k_prep(const int* __restrict__ adj, unsigned long long* __restrict__ bits,
            const float* __restrict__ W1, unsigned short* __restrict__ w1f)
{
    __shared__ float wt[64][65];
    const int t = threadIdx.x, bx = blockIdx.x;
    if (bx < NN) {
        const int wv = t >> 6, lane = t & 63;
        const int* ap = adj + (size_t)bx * NN;
        for (int w = wv; w < 64; w += 4) {
            unsigned long long m = __ballot(ap[w * 64 + lane] > 0);
            if (lane == 0) bits[(size_t)bx * 64 + w] = m;
        }
        return;
    }
    const int kt = (bx - NN) & 7, h = (bx - NN) >> 3;
    #pragma unroll
    for (int i = 0; i < 4; ++i) {
        const int f = t + 256 * i;
        const int r = f >> 4, c4 = f & 15;   // r = k_local, c4*4 = c
        const float4 v = *(const float4*)(W1 + ((size_t)(h * NFEAT) + kt * 64 + r) * NHID + c4 * 4);
        wt[r][c4 * 4 + 0] = v.x; wt[r][c4 * 4 + 1] = v.y;
        wt[r][c4 * 4 + 2] = v.z; wt[r][c4 * 4 + 3] = v.w;
    }
    __syncthreads();
    #pragma unroll
    for (int s = 0; s < 2; ++s) {
        const int o = t + s * 256;                   // octet id 0..511
        const int kg2 = o >> 8, rem = o & 255;
        const int nt = rem >> 6, lane2 = rem & 63;
        const int qq = lane2 >> 4, nn = lane2 & 15;
        const int kl = kg2 * 32 + qq * 8;            // k_local base
        const int c = nt * 16 + nn;
        uint4 w;
        w.x = pkbf(wt[kl + 0][c], wt[kl + 1][c]);
        w.y = pkbf(wt[kl + 2][c], wt[kl + 3][c]);
        w.z = pkbf(wt[kl + 4][c], wt[kl + 5][c]);
        w.w = pkbf(wt[kl + 6][c], wt[kl + 7][c]);
        *(uint4*)(w1f + (((size_t)h * 16 + kt * 2 + kg2) * 4 + nt) * 512 + lane2 * 8) = w;
    }
}

// ---------------------------------------------------------------------------
// feats1 = x @ W1 via MFMA (x cast in-register, W1 frag-major) -> f1bT +
// s1 + F1a/F2a. grid (64,8), 256 thr.
// ---------------------------------------------------------------------------
__global__ __launch_bounds__(256)
void k_feats1(const float* __restrict__ x, const unsigned short* __restrict__ w1f,
              const float* __restrict__ as1, const float* __restrict__ an1,
              unsigned short* __restrict__ f1bT, float* __restrict__ s1,
              float* __restrict__ F1a, float* __restrict__ F2a)
{
    const int t = threadIdx.x, wv = t >> 6, lane = t & 63;
    const int q = lane >> 4, n = lane & 15;
    const int h = blockIdx.y, R0 = blockIdx.x * 64;
    const int row = R0 + wv * 16 + n;
    const float* ap = x + (size_t)row * NFEAT;
    const unsigned short* wp = w1f + (size_t)h * 16 * 4 * 512 + lane * 8;
    f32x4 acc[4] = {{0.f,0.f,0.f,0.f},{0.f,0.f,0.f,0.f},{0.f,0.f,0.f,0.f},{0.f,0.f,0.f,0.f}};
    #pragma unroll 4
    for (int kg = 0; kg < 16; ++kg) {
        const float4 xa = *(const float4*)(ap + kg * 32 + q * 8);
        const float4 xb = *(const float4*)(ap + kg * 32 + q * 8 + 4);
        const bf16x8 af = mk8(pkbf(xa.x, xa.y), pkbf(xa.z, xa.w),
                              pkbf(xb.x, xb.y), pkbf(xb.z, xb.w));
        #pragma unroll
        for (int nt = 0; nt < 4; ++nt) {
            const bf16x8 bf = *(const bf16x8*)(wp + (size_t)(kg * 4 + nt) * 512);
            acc[nt] = __builtin_amdgcn_mfma_f32_16x16x32_bf16(af, bf, acc[nt], 0, 0, 0);
        }
    }
    #pragma unroll
    for (int nt = 0; nt < 4; ++nt) {
        uint2 w;
        w.x = pkbf(acc[nt][0], acc[nt][1]);
        w.y = pkbf(acc[nt][2], acc[nt][3]);
        *(uint2*)(f1bT + ((size_t)h * NHID + nt * 16 + n) * NN + R0 + wv * 16 + q * 4) = w;
    }
    float asv[4], anv[4];
    #pragma unroll
    for (int nt = 0; nt < 4; ++nt) {
        asv[nt] = as1[h * NHID + nt * 16 + n];
        anv[nt] = an1[h * NHID + nt * 16 + n];
    }
    #pragma unroll
    for (int i = 0; i < 4; ++i) {
        float ps = acc[0][i]*asv[0] + acc[1][i]*asv[1] + acc[2][i]*asv[2] + acc[3][i]*asv[3];
        float pn = acc[0][i]*anv[0] + acc[1][i]*anv[1] + acc[2][i]*anv[2] + acc[3][i]*anv[3];
        #pragma unroll
        for (int off = 8; off > 0; off >>= 1) {
            ps += __shfl_xor(ps, off, 64);
            pn += __shfl_xor(pn, off, 64);
        }
        if (n == 0) {
            const int idx = R0 + wv * 16 + q * 4 + i;
            s1[h * NN + idx] = ps;
            F1a[h * NN + idx] = __expf(pn - BND);
            F2a[h * NN + idx] = __expf(0.2f * (pn - BND));
        }
    }
}

// ---------------------------------------------------------------------------
// Layer-1 aggregation, barrier-free main loop.
// Grid (128,8) x 512 thr. Block = 32 rows of one head (R0..R0+31). Wave wv
// owns j-stream [wv*512, wv*512+512): 16 iters x 32-j tile, SINGLE-buffered
// in its PRIVATE LDS stream vT[wv] (no cross-wave sharing -> ZERO barriers;
// per-wave DS ops are in-order, compiler inserts lgkmcnt waits). Next tile
// is prefetched to regs before compute (T14), written to LDS after.
// LDS 40960 B + launch_bounds(512,6) (VGPR cap 85; R2 showed cap 32 ->
// catastrophic spill, R0 body needed 64) -> 3 blocks/CU = 24 waves/CU.
// Block-level B-panel reuse preserved (R1 showed removing it -> 684 MB HBM).
// ---------------------------------------------------------------------------
__global__ __launch_bounds__(512, 6)
void k_gat1(const unsigned short* __restrict__ f1bT, const float* __restrict__ s1,
            const float* __restrict__ F1, const float* __restrict__ F2,
            const unsigned long long* __restrict__ abits, const float* __restrict__ b1,
            unsigned short* __restrict__ hcatb)
{
    __shared__ __align__(16) char smem[8 * 64 * VSTR * 2];   // 40960 B
    unsigned short* vT = (unsigned short*)smem;              // [wv][64][VSTR]

    const int t = threadIdx.x, wv = t >> 6, lane = t & 63;
    const int q = lane >> 4, n = lane & 15;
    const int h = blockIdx.y, R0 = blockIdx.x * 32;
    const int rowA = R0 + n, rowB = R0 + 16 + n;

    const float vA = s1[h * NN + rowA] + BND, mhA = leaky(vA);
    const float vB = s1[h * NN + rowB] + BND, mhB = leaky(vB);
    const float E1A = __expf(vA - mhA), E2A = __expf(0.2f * vA - mhA);
    const float E1B = __expf(vB - mhB), E2B = __expf(0.2f * vB - mhB);

    const unsigned* arowA32 = (const unsigned*)abits + (size_t)rowA * 128 + wv * 16;
    const unsigned* arowB32 = (const unsigned*)abits + (size_t)rowB * 128 + wv * 16;
    const float* F1p = F1 + (size_t)h * NN + wv * 512;
    const float* F2p = F2 + (size_t)h * NN + wv * 512;

    // staging: lane stages col=lane of stream wv (64 B = 4 int4 per iter,
    // one full 64B cache line per lane). vme = this lane's LDS row.
    const unsigned short* sbase = f1bT + (size_t)(h * NHID + lane) * NN + wv * 512;
    unsigned short* vme = vT + (wv * 64 + lane) * VSTR;
    const unsigned short* tb = vT + (size_t)wv * 64 * VSTR + q * 8;

    f32x4 accA[4] = {{0.f,0.f,0.f,0.f},{0.f,0.f,0.f,0.f},{0.f,0.f,0.f,0.f},{0.f,0.f,0.f,0.f}};
    f32x4 accB[4] = {{0.f,0.f,0.f,0.f},{0.f,0.f,0.f,0.f},{0.f,0.f,0.f,0.f},{0.f,0.f,0.f,0.f}};
    float lsA = 0.f, lsB = 0.f;

    {   // preload it=0 into this wave's stream
        int4 c0 = *(const int4*)(sbase);
        int4 c1 = *(const int4*)(sbase + 8);
        int4 c2 = *(const int4*)(sbase + 16);
        int4 c3 = *(const int4*)(sbase + 24);
        *(int4*)(vme) = c0;      *(int4*)(vme + 8) = c1;
        *(int4*)(vme + 16) = c2; *(int4*)(vme + 24) = c3;
    }

    for (int it = 0; it < 16; ++it) {
        int4 p0, p1, p2, p3;
        if (it < 15) {           // prefetch next tile to regs (latency hides under compute)
            const unsigned short* sb = sbase + (it + 1) * 32;
            p0 = *(const int4*)(sb);      p1 = *(const int4*)(sb + 8);
            p2 = *(const int4*)(sb + 16); p3 = *(const int4*)(sb + 24);
        }
        const int j0 = it * 32, kb = q * 8;
        const unsigned aA = arowA32[it], aB = arowB32[it];
        const float4 f1a = *(const float4*)(F1p + j0 + kb);
        const float4 f1b = *(const float4*)(F1p + j0 + kb + 4);
        const float4 f2a = *(const float4*)(F2p + j0 + kb);
        const float4 f2b = *(const float4*)(F2p + j0 + kb + 4);
        const float F1v[8] = {f1a.x, f1a.y, f1a.z, f1a.w, f1b.x, f1b.y, f1b.z, f1b.w};
        const float F2v[8] = {f2a.x, f2a.y, f2a.z, f2a.w, f2b.x, f2b.y, f2b.z, f2b.w};
        const unsigned bA8 = (aA >> kb) & 0xffu;
        const unsigned bB8 = (aB >> kb) & 0xffu;
        unsigned uA[4], uB[4];
        #pragma unroll
        for (int jp = 0; jp < 4; ++jp) {
            float a0 = fmaxf(E1A * F1v[2*jp],   E2A * F2v[2*jp]);
            float a1 = fmaxf(E1A * F1v[2*jp+1], E2A * F2v[2*jp+1]);
            a0 = __uint_as_float(__float_as_uint(a0) & bmask(bA8, 2*jp));
            a1 = __uint_as_float(__float_as_uint(a1) & bmask(bA8, 2*jp+1));
            lsA += a0 + a1;
            uA[jp] = pkbf(a0, a1);
            float b0  = fmaxf(E1B * F1v[2*jp],   E2B * F2v[2*jp]);
            float b1v = fmaxf(E1B * F1v[2*jp+1], E2B * F2v[2*jp+1]);
            b0  = __uint_as_float(__float_as_uint(b0)  & bmask(bB8, 2*jp));
            b1v = __uint_as_float(__float_as_uint(b1v) & bmask(bB8, 2*jp+1));
            lsB += b0 + b1v;
            uB[jp] = pkbf(b0, b1v);
        }
        const bf16x8 afA = mk8(uA[0], uA[1], uA[2], uA[3]);
        const bf16x8 afB = mk8(uB[0], uB[1], uB[2], uB[3]);
        #pragma unroll
        for (int nt = 0; nt < 4; ++nt) {
            const bf16x8 bf = *(const bf16x8*)(tb + (nt * 16 + n) * VSTR);
            accA[nt] = __builtin_amdgcn_mfma_f32_16x16x32_bf16(afA, bf, accA[nt], 0, 0, 0);
            accB[nt] = __builtin_amdgcn_mfma_f32_16x16x32_bf16(afB, bf, accB[nt], 0, 0, 0);
        }
        if (it < 15) {           // in-order DS per wave: safe single-buffer overwrite
            *(int4*)(vme) = p0;      *(int4*)(vme + 8) = p1;
            *(int4*)(vme + 16) = p2; *(int4*)(vme + 24) = p3;
        }
    }

    lsA += __shfl_xor(lsA, 16, 64); lsA += __shfl_xor(lsA, 32, 64);
    lsB += __shfl_xor(lsB, 16, 64); lsB += __shfl_xor(lsB, 32, 64);

    // epilogue: reuse smem. cmbf [8 jq][16 rows][68] = 34816 B + lwf [8][16]
    float (*cmbf)[16][68] = (float (*)[16][68])smem;
    float (*lwf)[16] = (float (*)[16])(smem + 8 * 16 * 68 * 4);

    __syncthreads();             // all waves done reading their vT streams

    // ---- pass A: rows R0 .. R0+15 ----
    #pragma unroll
    for (int nt = 0; nt < 4; ++nt)
        #pragma unroll
        for (int i = 0; i < 4; ++i)
            cmbf[wv][q * 4 + i][nt * 16 + n] = accA[nt][i];
    if (q == 0) lwf[wv][n] = lsA;
    __syncthreads();
    {
        const int r = t >> 5, c0 = (t & 31) * 2;
        float t0 = 0.f, t1 = 0.f, lt = 0.f;
        #pragma unroll
        for (int jj = 0; jj < 8; ++jj) {
            const float2 v = *(const float2*)&cmbf[jj][r][c0];
            t0 += v.x; t1 += v.y;
            lt += lwf[jj][r];
        }
        const float o0 = fmaxf(t0 / lt + b1[h * NHID + c0], 0.f);     // relu; elu(x>=0)=x
        const float o1 = fmaxf(t1 / lt + b1[h * NHID + c0 + 1], 0.f);
        *(unsigned*)(hcatb + (size_t)(R0 + r) * (H1 * NHID) + h * NHID + c0) = pkbf(o0, o1);
    }
    __syncthreads();

    // ---- pass B: rows R0+16 .. R0+31 ----
    #pragma unroll
    for (int nt = 0; nt < 4; ++nt)
        #pragma unroll
        for (int i = 0; i < 4; ++i)
            cmbf[wv][q * 4 + i][nt * 16 + n] = accB[nt][i];
    if (q == 0) lwf[wv][n] = lsB;
    __syncthreads();
    {
        const int r = t >> 5, c0 = (t & 31) * 2;
        float t0 = 0.f, t1 = 0.f, lt = 0.f;
        #pragma unroll
        for (int jj = 0; jj < 8; ++jj) {
            const float2 v = *(const float2*)&cmbf[jj][r][c0];
            t0 += v.x; t1 += v.y;
            lt += lwf[jj][r];
        }
        const float o0 = fmaxf(t0 / lt + b1[h * NHID + c0], 0.f);
        const float o1 = fmaxf(t1 / lt + b1[h * NHID + c0 + 1], 0.f);
        *(unsigned*)(hcatb + (size_t)(R0 + 16 + r) * (H1 * NHID) + h * NHID + c0) = pkbf(o0, o1);
    }
}

// ---------------------------------------------------------------------------
// feats2 = hcatb @ W2 (W2 -> bf16 LDS transpose in-kernel) -> f2bT + s2 +
// F1b/F2b. grid 128, 128 thr.
// ---------------------------------------------------------------------------
__global__ __launch_bounds__(128)
void k_feats2(const unsigned short* __restrict__ hcatb, const float* __restrict__ W2,
              const float* __restrict__ as2, const float* __restrict__ an2,
              unsigned short* __restrict__ f2bT, float* __restrict__ s2,
              float* __restrict__ F1b, float* __restrict__ F2b)
{
    __shared__ __align__(16) unsigned short w2T[NCLS][520];
    const int t = threadIdx.x, wv = t >> 6, lane = t & 63;
    const int q = lane >> 4, n = lane & 15;
    #pragma unroll
    for (int i = 0; i < 16; ++i) {
        const int f4 = t + 128 * i;
        const float4 v = ((const float4*)W2)[f4];
        const int k = f4 >> 2, c0 = (f4 & 3) * 4;
        w2T[c0 + 0][k] = f2bf(v.x); w2T[c0 + 1][k] = f2bf(v.y);
        w2T[c0 + 2][k] = f2bf(v.z); w2T[c0 + 3][k] = f2bf(v.w);
    }
    __syncthreads();

    const int R0 = blockIdx.x * 32;
    const int row = R0 + wv * 16 + n;
    const unsigned short* ap = hcatb + (size_t)row * NFEAT;
    f32x4 acc = {0.f, 0.f, 0.f, 0.f};
    #pragma unroll 4
    for (int k0 = 0; k0 < NFEAT; k0 += 32) {
        const bf16x8 af = *(const bf16x8*)(ap + k0 + q * 8);
        const bf16x8 bf = *(const bf16x8*)&w2T[n][k0 + q * 8];
        acc = __builtin_amdgcn_mfma_f32_16x16x32_bf16(af, bf, acc, 0, 0, 0);
    }
    uint2 w;
    w.x = pkbf(acc[0], acc[1]);
    w.y = pkbf(acc[2], acc[3]);
    *(uint2*)(f2bT + (size_t)n * NN + R0 + wv * 16 + q * 4) = w;
    const float asv = as2[n], anv = an2[n];
    #pragma unroll
    for (int i = 0; i < 4; ++i) {
        float ps = acc[i] * asv, pn = acc[i] * anv;
        #pragma unroll
        for (int off = 8; off > 0; off >>= 1) {
            ps += __shfl_xor(ps, off, 64);
            pn += __shfl_xor(pn, off, 64);
        }
        if (n == 0) {
            const int idx = R0 + wv * 16 + q * 4 + i;
            s2[idx] = ps;
            F1b[idx] = __expf(pn - BND);
            F2b[idx] = __expf(0.2f * (pn - BND));
        }
    }
}

// ---------------------------------------------------------------------------
// Layer-2 aggregation + relu + log_softmax. 1024 thr = 16 wave j-sixteenths.
// ---------------------------------------------------------------------------
__global__ __launch_bounds__(1024)
void k_gat2(const unsigned short* __restrict__ f2bT, const float* __restrict__ s2,
            const float* __restrict__ F1, const float* __restrict__ F2,
            const unsigned long long* __restrict__ abits, const float* __restrict__ b2,
            float* __restrict__ out)
{
    __shared__ float cmb[16][16][17];
    __shared__ float lw[16][16];
    const int t = threadIdx.x, wv = t >> 6, lane = t & 63;
    const int q = lane >> 4, n = lane & 15;
    const int R0 = blockIdx.x * 16, row = R0 + n;
    const float v = s2[row] + BND, mhat = leaky(v);
    const float E1 = __expf(v - mhat), E2 = __expf(0.2f * v - mhat);
    const unsigned long long* arow = abits + (size_t)row * 64;

    f32x4 acc = {0.f, 0.f, 0.f, 0.f};
    float lsum = 0.f;
    const int jbeg = wv * 256;
    for (int j0 = jbeg; j0 < jbeg + 256; j0 += 64) {
        const unsigned long long a64 = arow[j0 >> 6];
        #pragma unroll
        for (int ch = 0; ch < 2; ++ch) {
            const int kb = ch * 32 + q * 8;
            const float4 f1a = *(const float4*)(F1 + j0 + kb);
            const float4 f1b = *(const float4*)(F1 + j0 + kb + 4);
            const float4 f2a = *(const float4*)(F2 + j0 + kb);
            const float4 f2b = *(const float4*)(F2 + j0 + kb + 4);
            const float F1v[8] = {f1a.x, f1a.y, f1a.z, f1a.w, f1b.x, f1b.y, f1b.z, f1b.w};
            const float F2v[8] = {f2a.x, f2a.y, f2a.z, f2a.w, f2b.x, f2b.y, f2b.z, f2b.w};
            const unsigned b8 = (unsigned)(a64 >> kb) & 0xffu;
            unsigned au[4];
            #pragma unroll
            for (int jp = 0; jp < 4; ++jp) {
                float p0 = fmaxf(E1 * F1v[2*jp],   E2 * F2v[2*jp]);
                float p1 = fmaxf(E1 * F1v[2*jp+1], E2 * F2v[2*jp+1]);
                p0 = __uint_as_float(__float_as_uint(p0) & bmask(b8, 2*jp));
                p1 = __uint_as_float(__float_as_uint(p1) & bmask(b8, 2*jp+1));
                lsum += p0 + p1;
                au[jp] = pkbf(p0, p1);
            }
            const bf16x8 af = mk8(au[0], au[1], au[2], au[3]);
            const bf16x8 bf = *(const bf16x8*)(f2bT + (size_t)n * NN + j0 + kb);
            acc = __builtin_amdgcn_mfma_f32_16x16x32_bf16(af, bf, acc, 0, 0, 0);
        }
    }
    lsum += __shfl_xor(lsum, 16, 64);
    lsum += __shfl_xor(lsum, 32, 64);
    #pragma unroll
    for (int i = 0; i < 4; ++i) cmb[wv][q * 4 + i][n] = acc[i];
    if (q == 0) lw[wv][n] = lsum;
    __syncthreads();

    if (t < 256) {
        const int r = t >> 4, c = t & 15;
        float tot = 0.f, lt = 0.f;
        #pragma unroll
        for (int w16 = 0; w16 < 16; ++w16) { tot += cmb[w16][r][c]; lt += lw[w16][r]; }
        float val = fmaxf(tot / lt + b2[c], 0.f);
        float mx = val;
        #pragma unroll
        for (int off = 1; off < 16; off <<= 1) mx = fmaxf(mx, __shfl_xor(mx, off, 64));
        const float e = __expf(val - mx);
        float se = e;
        #pragma unroll
        for (int off = 1; off < 16; off <<= 1) se += __shfl_xor(se, off, 64);
        out[(size_t)(R0 + r) * NCLS + c] = val - mx - __logf(se);
    }
}

// ---------------------------------------------------------------------------
extern "C" void kernel_launch(void* const* d_in, const int* in_sizes, int n_in,
                              void* d_out, int out_size, void* d_ws, size_t ws_size,
                              hipStream_t stream)
{
    const float* x   = (const float*)d_in[0];
    const int*   adj = (const int*)  d_in[1];
    const float* W1  = (const float*)d_in[2];
    const float* b1  = (const float*)d_in[3];
    const float* as1 = (const float*)d_in[4];
    const float* an1 = (const float*)d_in[5];
    const float* W2  = (const float*)d_in[6];
    const float* b2  = (const float*)d_in[7];
    const float* as2 = (const float*)d_in[8];
    const float* an2 = (const float*)d_in[9];
    float* out = (float*)d_out;

    char* ws = (char*)d_ws;
    unsigned long long* abits = (unsigned long long*)(ws);            // 2 MB
    unsigned short* f1bT  = (unsigned short*)(ws + (2u << 20));       // 4 MB
    unsigned short* hcatb = (unsigned short*)(ws + (6u << 20));       // 4 MB
    unsigned short* w1f   = (unsigned short*)(ws + (10u << 20));      // 512 KB
    char* ws2 = ws + (10u << 20) + (512u << 10);
    float* s1   = (float*)(ws2);                                      // 128 KB
    float* F1a  = (float*)(ws2 + (128u << 10));                       // 128 KB
    float* F2a  = (float*)(ws2 + (256u << 10));                       // 128 KB
    unsigned short* f2bT = (unsigned short*)(ws2 + (384u << 10));     // 128 KB
    float* s2   = (float*)(ws2 + (512u << 10));                       // 16 KB
    float* F1b  = (float*)(ws2 + (528u << 10));                       // 16 KB
    float* F2b  = (float*)(ws2 + (544u << 10));                       // 16 KB

    k_prep  <<<dim3(NN + 64),     256, 0, stream>>>(adj, abits, W1, w1f);
    k_feats1<<<dim3(NN / 64, H1), 256, 0, stream>>>(x, w1f, as1, an1, f1bT, s1, F1a, F2a);
    k_gat1  <<<dim3(NN / 32, H1), 512, 0, stream>>>(f1bT, s1, F1a, F2a, abits, b1, hcatb);
    k_feats2<<<dim3(NN / 32),     128, 0, stream>>>(hcatb, W2, as2, an2, f2bT, s2, F1b, F2b);
    k_gat2  <<<dim3(NN / 16),     1024, 0, stream>>>(f2bT, s2, F1b, F2b, abits, b2, out);
}

// Round 5
// 296.569 us; speedup vs baseline: 2.0195x; 1.2050x over previous
//
#include <hip/hip_runtime.h>

#define NN 4096
#define NFEAT 512
#define NHID 64
#define H1 8
#define NCLS 16
#define BND 40.0f   // static upper bound for nbmax (true ~13 layer1, ~0.5 layer2)
#define VSTR 40     // bf16 elems per vT row: 32 j + 8 pad = 80B rows, 16B-aligned

typedef short bf16x8 __attribute__((ext_vector_type(8)));
typedef float f32x4 __attribute__((ext_vector_type(4)));

__device__ __forceinline__ unsigned short f2bf(float f) {
    unsigned u = __float_as_uint(f);
    u += 0x7fffu + ((u >> 16) & 1u);          // RNE
    return (unsigned short)(u >> 16);
}
__device__ __forceinline__ float leaky(float v) { return fmaxf(v, 0.2f * v); }
// pack two fp32 -> dword of two bf16 (round-half-up, 3 instr per 2 values)
__device__ __forceinline__ unsigned pkbf(float lo, float hi) {
    return __builtin_amdgcn_perm(__float_as_uint(hi) + 0x8000u,
                                 __float_as_uint(lo) + 0x8000u, 0x07060302u);
}
__device__ __forceinline__ bf16x8 mk8(unsigned a, unsigned b, unsigned c, unsigned d) {
    union { unsigned u[4]; bf16x8 v; } cv;
    cv.u[0] = a; cv.u[1] = b; cv.u[2] = c; cv.u[3] = d; return cv.v;
}
// bit i of b -> 0x00000000 / 0xFFFFFFFF in 1-2 VALU (v_bfe_i32 width=1)
__device__ __forceinline__ unsigned bmask(unsigned b, int i) {
#if __has_builtin(__builtin_amdgcn_sbfe)
    return (unsigned)__builtin_amdgcn_sbfe((int)b, (unsigned)i, 1u);
#else
    return 0u - ((b >> i) & 1u);
#endif
}

// ---------------------------------------------------------------------------
// Dual-role: bx < 4096 -> pack adj row; else -> W1 -> MFMA-frag-major bf16.
// w1f element ((h*16+kg)*4+nt)*512 + lane*8 + e  =  W1[h][kg*32+q*8+e][nt*16+n]
// with lane = q*16+n. Consumer B-loads are then lane-contiguous (coalesced).
// ---------------------------------------------------------------------------
__global__ __launch_bounds__(256)
void k_prep(const int* __restrict__ adj, unsigned long long* __restrict__ bits,
            const float* __restrict__ W1, unsigned short* __restrict__ w1f)
{
    __shared__ float wt[64][65];
    const int t = threadIdx.x, bx = blockIdx.x;
    if (bx < NN) {
        const int wv = t >> 6, lane = t & 63;
        const int* ap = adj + (size_t)bx * NN;
        for (int w = wv; w < 64; w += 4) {
            unsigned long long m = __ballot(ap[w * 64 + lane] > 0);
            if (lane == 0) bits[(size_t)bx * 64 + w] = m;
        }
        return;
    }
    const int kt = (bx - NN) & 7, h = (bx - NN) >> 3;
    #pragma unroll
    for (int i = 0; i < 4; ++i) {
        const int f = t + 256 * i;
        const int r = f >> 4, c4 = f & 15;   // r = k_local, c4*4 = c
        const float4 v = *(const float4*)(W1 + ((size_t)(h * NFEAT) + kt * 64 + r) * NHID + c4 * 4);
        wt[r][c4 * 4 + 0] = v.x; wt[r][c4 * 4 + 1] = v.y;
        wt[r][c4 * 4 + 2] = v.z; wt[r][c4 * 4 + 3] = v.w;
    }
    __syncthreads();
    #pragma unroll
    for (int s = 0; s < 2; ++s) {
        const int o = t + s * 256;                   // octet id 0..511
        const int kg2 = o >> 8, rem = o & 255;
        const int nt = rem >> 6, lane2 = rem & 63;
        const int qq = lane2 >> 4, nn = lane2 & 15;
        const int kl = kg2 * 32 + qq * 8;            // k_local base
        const int c = nt * 16 + nn;
        uint4 w;
        w.x = pkbf(wt[kl + 0][c], wt[kl + 1][c]);
        w.y = pkbf(wt[kl + 2][c], wt[kl + 3][c]);
        w.z = pkbf(wt[kl + 4][c], wt[kl + 5][c]);
        w.w = pkbf(wt[kl + 6][c], wt[kl + 7][c]);
        *(uint4*)(w1f + (((size_t)h * 16 + kt * 2 + kg2) * 4 + nt) * 512 + lane2 * 8) = w;
    }
}

// ---------------------------------------------------------------------------
// feats1 = x @ W1 via MFMA (x cast in-register, W1 frag-major) -> f1bT +
// s1 + F1a/F2a. grid (64,8), 256 thr.
// ---------------------------------------------------------------------------
__global__ __launch_bounds__(256)
void k_feats1(const float* __restrict__ x, const unsigned short* __restrict__ w1f,
              const float* __restrict__ as1, const float* __restrict__ an1,
              unsigned short* __restrict__ f1bT, float* __restrict__ s1,
              float* __restrict__ F1a, float* __restrict__ F2a)
{
    const int t = threadIdx.x, wv = t >> 6, lane = t & 63;
    const int q = lane >> 4, n = lane & 15;
    const int h = blockIdx.y, R0 = blockIdx.x * 64;
    const int row = R0 + wv * 16 + n;
    const float* ap = x + (size_t)row * NFEAT;
    const unsigned short* wp = w1f + (size_t)h * 16 * 4 * 512 + lane * 8;
    f32x4 acc[4] = {{0.f,0.f,0.f,0.f},{0.f,0.f,0.f,0.f},{0.f,0.f,0.f,0.f},{0.f,0.f,0.f,0.f}};
    #pragma unroll 4
    for (int kg = 0; kg < 16; ++kg) {
        const float4 xa = *(const float4*)(ap + kg * 32 + q * 8);
        const float4 xb = *(const float4*)(ap + kg * 32 + q * 8 + 4);
        const bf16x8 af = mk8(pkbf(xa.x, xa.y), pkbf(xa.z, xa.w),
                              pkbf(xb.x, xb.y), pkbf(xb.z, xb.w));
        #pragma unroll
        for (int nt = 0; nt < 4; ++nt) {
            const bf16x8 bf = *(const bf16x8*)(wp + (size_t)(kg * 4 + nt) * 512);
            acc[nt] = __builtin_amdgcn_mfma_f32_16x16x32_bf16(af, bf, acc[nt], 0, 0, 0);
        }
    }
    #pragma unroll
    for (int nt = 0; nt < 4; ++nt) {
        uint2 w;
        w.x = pkbf(acc[nt][0], acc[nt][1]);
        w.y = pkbf(acc[nt][2], acc[nt][3]);
        *(uint2*)(f1bT + ((size_t)h * NHID + nt * 16 + n) * NN + R0 + wv * 16 + q * 4) = w;
    }
    float asv[4], anv[4];
    #pragma unroll
    for (int nt = 0; nt < 4; ++nt) {
        asv[nt] = as1[h * NHID + nt * 16 + n];
        anv[nt] = an1[h * NHID + nt * 16 + n];
    }
    #pragma unroll
    for (int i = 0; i < 4; ++i) {
        float ps = acc[0][i]*asv[0] + acc[1][i]*asv[1] + acc[2][i]*asv[2] + acc[3][i]*asv[3];
        float pn = acc[0][i]*anv[0] + acc[1][i]*anv[1] + acc[2][i]*anv[2] + acc[3][i]*anv[3];
        #pragma unroll
        for (int off = 8; off > 0; off >>= 1) {
            ps += __shfl_xor(ps, off, 64);
            pn += __shfl_xor(pn, off, 64);
        }
        if (n == 0) {
            const int idx = R0 + wv * 16 + q * 4 + i;
            s1[h * NN + idx] = ps;
            F1a[h * NN + idx] = __expf(pn - BND);
            F2a[h * NN + idx] = __expf(0.2f * (pn - BND));
        }
    }
}

// ---------------------------------------------------------------------------
// Layer-1 aggregation, barrier-free main loop.
// Grid (128,8) x 512 thr. Block = 32 rows of one head (R0..R0+31). Wave wv
// owns j-stream [wv*512, wv*512+512): 16 iters x 32-j tile, SINGLE-buffered
// in its PRIVATE LDS stream vT[wv] (no cross-wave sharing -> ZERO barriers;
// per-wave DS ops are in-order, compiler inserts lgkmcnt waits). Next tile
// is prefetched to regs before compute (T14), written to LDS after.
// VGPR law (measured R0/R2/R4): cap = 256 / launch_bounds_arg2. Working set
// needs ~64 -> arg2 = 4 (cap 64; R0's identical body fit with 0 spill).
// LDS 40960 B -> 4 blocks/CU x 8 waves = 32 waves/CU (HW max).
// Block-level B-panel reuse preserved (R1 showed removing it -> 684 MB HBM).
// ---------------------------------------------------------------------------
__global__ __launch_bounds__(512, 4)
void k_gat1(const unsigned short* __restrict__ f1bT, const float* __restrict__ s1,
            const float* __restrict__ F1, const float* __restrict__ F2,
            const unsigned long long* __restrict__ abits, const float* __restrict__ b1,
            unsigned short* __restrict__ hcatb)
{
    __shared__ __align__(16) char smem[8 * 64 * VSTR * 2];   // 40960 B
    unsigned short* vT = (unsigned short*)smem;              // [wv][64][VSTR]

    const int t = threadIdx.x, wv = t >> 6, lane = t & 63;
    const int q = lane >> 4, n = lane & 15;
    const int h = blockIdx.y, R0 = blockIdx.x * 32;
    const int rowA = R0 + n, rowB = R0 + 16 + n;

    const float vA = s1[h * NN + rowA] + BND, mhA = leaky(vA);
    const float vB = s1[h * NN + rowB] + BND, mhB = leaky(vB);
    const float E1A = __expf(vA - mhA), E2A = __expf(0.2f * vA - mhA);
    const float E1B = __expf(vB - mhB), E2B = __expf(0.2f * vB - mhB);

    const unsigned* arowA32 = (const unsigned*)abits + (size_t)rowA * 128 + wv * 16;
    const unsigned* arowB32 = (const unsigned*)abits + (size_t)rowB * 128 + wv * 16;
    const float* F1p = F1 + (size_t)h * NN + wv * 512;
    const float* F2p = F2 + (size_t)h * NN + wv * 512;

    // staging: lane stages col=lane of stream wv (64 B = 4 int4 per iter,
    // one full 64B cache line per lane). vme = this lane's LDS row.
    const unsigned short* sbase = f1bT + (size_t)(h * NHID + lane) * NN + wv * 512;
    unsigned short* vme = vT + (wv * 64 + lane) * VSTR;
    const unsigned short* tb = vT + (size_t)wv * 64 * VSTR + q * 8;

    f32x4 accA[4] = {{0.f,0.f,0.f,0.f},{0.f,0.f,0.f,0.f},{0.f,0.f,0.f,0.f},{0.f,0.f,0.f,0.f}};
    f32x4 accB[4] = {{0.f,0.f,0.f,0.f},{0.f,0.f,0.f,0.f},{0.f,0.f,0.f,0.f},{0.f,0.f,0.f,0.f}};
    float lsA = 0.f, lsB = 0.f;

    {   // preload it=0 into this wave's stream
        int4 c0 = *(const int4*)(sbase);
        int4 c1 = *(const int4*)(sbase + 8);
        int4 c2 = *(const int4*)(sbase + 16);
        int4 c3 = *(const int4*)(sbase + 24);
        *(int4*)(vme) = c0;      *(int4*)(vme + 8) = c1;
        *(int4*)(vme + 16) = c2; *(int4*)(vme + 24) = c3;
    }

    for (int it = 0; it < 16; ++it) {
        int4 p0, p1, p2, p3;
        if (it < 15) {           // prefetch next tile to regs (latency hides under compute)
            const unsigned short* sb = sbase + (it + 1) * 32;
            p0 = *(const int4*)(sb);      p1 = *(const int4*)(sb + 8);
            p2 = *(const int4*)(sb + 16); p3 = *(const int4*)(sb + 24);
        }
        const int j0 = it * 32, kb = q * 8;
        const unsigned aA = arowA32[it], aB = arowB32[it];
        const float4 f1a = *(const float4*)(F1p + j0 + kb);
        const float4 f1b = *(const float4*)(F1p + j0 + kb + 4);
        const float4 f2a = *(const float4*)(F2p + j0 + kb);
        const float4 f2b = *(const float4*)(F2p + j0 + kb + 4);
        const float F1v[8] = {f1a.x, f1a.y, f1a.z, f1a.w, f1b.x, f1b.y, f1b.z, f1b.w};
        const float F2v[8] = {f2a.x, f2a.y, f2a.z, f2a.w, f2b.x, f2b.y, f2b.z, f2b.w};
        const unsigned bA8 = (aA >> kb) & 0xffu;
        const unsigned bB8 = (aB >> kb) & 0xffu;
        unsigned uA[4], uB[4];
        #pragma unroll
        for (int jp = 0; jp < 4; ++jp) {
            float a0 = fmaxf(E1A * F1v[2*jp],   E2A * F2v[2*jp]);
            float a1 = fmaxf(E1A * F1v[2*jp+1], E2A * F2v[2*jp+1]);
            a0 = __uint_as_float(__float_as_uint(a0) & bmask(bA8, 2*jp));
            a1 = __uint_as_float(__float_as_uint(a1) & bmask(bA8, 2*jp+1));
            lsA += a0 + a1;
            uA[jp] = pkbf(a0, a1);
            float b0  = fmaxf(E1B * F1v[2*jp],   E2B * F2v[2*jp]);
            float b1v = fmaxf(E1B * F1v[2*jp+1], E2B * F2v[2*jp+1]);
            b0  = __uint_as_float(__float_as_uint(b0)  & bmask(bB8, 2*jp));
            b1v = __uint_as_float(__float_as_uint(b1v) & bmask(bB8, 2*jp+1));
            lsB += b0 + b1v;
            uB[jp] = pkbf(b0, b1v);
        }
        const bf16x8 afA = mk8(uA[0], uA[1], uA[2], uA[3]);
        const bf16x8 afB = mk8(uB[0], uB[1], uB[2], uB[3]);
        #pragma unroll
        for (int nt = 0; nt < 4; ++nt) {
            const bf16x8 bf = *(const bf16x8*)(tb + (nt * 16 + n) * VSTR);
            accA[nt] = __builtin_amdgcn_mfma_f32_16x16x32_bf16(afA, bf, accA[nt], 0, 0, 0);
            accB[nt] = __builtin_amdgcn_mfma_f32_16x16x32_bf16(afB, bf, accB[nt], 0, 0, 0);
        }
        if (it < 15) {           // in-order DS per wave: safe single-buffer overwrite
            *(int4*)(vme) = p0;      *(int4*)(vme + 8) = p1;
            *(int4*)(vme + 16) = p2; *(int4*)(vme + 24) = p3;
        }
    }

    lsA += __shfl_xor(lsA, 16, 64); lsA += __shfl_xor(lsA, 32, 64);
    lsB += __shfl_xor(lsB, 16, 64); lsB += __shfl_xor(lsB, 32, 64);

    // epilogue: reuse smem. cmbf [8 jq][16 rows][68] = 34816 B + lwf [8][16]
    float (*cmbf)[16][68] = (float (*)[16][68])smem;
    float (*lwf)[16] = (float (*)[16])(smem + 8 * 16 * 68 * 4);

    __syncthreads();             // all waves done reading their vT streams

    // ---- pass A: rows R0 .. R0+15 ----
    #pragma unroll
    for (int nt = 0; nt < 4; ++nt)
        #pragma unroll
        for (int i = 0; i < 4; ++i)
            cmbf[wv][q * 4 + i][nt * 16 + n] = accA[nt][i];
    if (q == 0) lwf[wv][n] = lsA;
    __syncthreads();
    {
        const int r = t >> 5, c0 = (t & 31) * 2;
        float t0 = 0.f, t1 = 0.f, lt = 0.f;
        #pragma unroll
        for (int jj = 0; jj < 8; ++jj) {
            const float2 v = *(const float2*)&cmbf[jj][r][c0];
            t0 += v.x; t1 += v.y;
            lt += lwf[jj][r];
        }
        const float o0 = fmaxf(t0 / lt + b1[h * NHID + c0], 0.f);     // relu; elu(x>=0)=x
        const float o1 = fmaxf(t1 / lt + b1[h * NHID + c0 + 1], 0.f);
        *(unsigned*)(hcatb + (size_t)(R0 + r) * (H1 * NHID) + h * NHID + c0) = pkbf(o0, o1);
    }
    __syncthreads();

    // ---- pass B: rows R0+16 .. R0+31 ----
    #pragma unroll
    for (int nt = 0; nt < 4; ++nt)
        #pragma unroll
        for (int i = 0; i < 4; ++i)
            cmbf[wv][q * 4 + i][nt * 16 + n] = accB[nt][i];
    if (q == 0) lwf[wv][n] = lsB;
    __syncthreads();
    {
        const int r = t >> 5, c0 = (t & 31) * 2;
        float t0 = 0.f, t1 = 0.f, lt = 0.f;
        #pragma unroll
        for (int jj = 0; jj < 8; ++jj) {
            const float2 v = *(const float2*)&cmbf[jj][r][c0];
            t0 += v.x; t1 += v.y;
            lt += lwf[jj][r];
        }
        const float o0 = fmaxf(t0 / lt + b1[h * NHID + c0], 0.f);
        const float o1 = fmaxf(t1 / lt + b1[h * NHID + c0 + 1], 0.f);
        *(unsigned*)(hcatb + (size_t)(R0 + 16 + r) * (H1 * NHID) + h * NHID + c0) = pkbf(o0, o1);
    }
}

// ---------------------------------------------------------------------------
// feats2 = hcatb @ W2 (W2 -> bf16 LDS transpose in-kernel) -> f2bT + s2 +
// F1b/F2b. grid 128, 128 thr.
// ---------------------------------------------------------------------------
__global__ __launch_bounds__(128)
void k_feats2(const unsigned short* __restrict__ hcatb, const float* __restrict__ W2,
              const float* __restrict__ as2, const float* __restrict__ an2,
              unsigned short* __restrict__ f2bT, float* __restrict__ s2,
              float* __restrict__ F1b, float* __restrict__ F2b)
{
    __shared__ __align__(16) unsigned short w2T[NCLS][520];
    const int t = threadIdx.x, wv = t >> 6, lane = t & 63;
    const int q = lane >> 4, n = lane & 15;
    #pragma unroll
    for (int i = 0; i < 16; ++i) {
        const int f4 = t + 128 * i;
        const float4 v = ((const float4*)W2)[f4];
        const int k = f4 >> 2, c0 = (f4 & 3) * 4;
        w2T[c0 + 0][k] = f2bf(v.x); w2T[c0 + 1][k] = f2bf(v.y);
        w2T[c0 + 2][k] = f2bf(v.z); w2T[c0 + 3][k] = f2bf(v.w);
    }
    __syncthreads();

    const int R0 = blockIdx.x * 32;
    const int row = R0 + wv * 16 + n;
    const unsigned short* ap = hcatb + (size_t)row * NFEAT;
    f32x4 acc = {0.f, 0.f, 0.f, 0.f};
    #pragma unroll 4
    for (int k0 = 0; k0 < NFEAT; k0 += 32) {
        const bf16x8 af = *(const bf16x8*)(ap + k0 + q * 8);
        const bf16x8 bf = *(const bf16x8*)&w2T[n][k0 + q * 8];
        acc = __builtin_amdgcn_mfma_f32_16x16x32_bf16(af, bf, acc, 0, 0, 0);
    }
    uint2 w;
    w.x = pkbf(acc[0], acc[1]);
    w.y = pkbf(acc[2], acc[3]);
    *(uint2*)(f2bT + (size_t)n * NN + R0 + wv * 16 + q * 4) = w;
    const float asv = as2[n], anv = an2[n];
    #pragma unroll
    for (int i = 0; i < 4; ++i) {
        float ps = acc[i] * asv, pn = acc[i] * anv;
        #pragma unroll
        for (int off = 8; off > 0; off >>= 1) {
            ps += __shfl_xor(ps, off, 64);
            pn += __shfl_xor(pn, off, 64);
        }
        if (n == 0) {
            const int idx = R0 + wv * 16 + q * 4 + i;
            s2[idx] = ps;
            F1b[idx] = __expf(pn - BND);
            F2b[idx] = __expf(0.2f * (pn - BND));
        }
    }
}

// ---------------------------------------------------------------------------
// Layer-2 aggregation + relu + log_softmax. 1024 thr = 16 wave j-sixteenths.
// ---------------------------------------------------------------------------
__global__ __launch_bounds__(1024)
void k_gat2(const unsigned short* __restrict__ f2bT, const float* __restrict__ s2,
            const float* __restrict__ F1, const float* __restrict__ F2,
            const unsigned long long* __restrict__ abits, const float* __restrict__ b2,
            float* __restrict__ out)
{
    __shared__ float cmb[16][16][17];
    __shared__ float lw[16][16];
    const int t = threadIdx.x, wv = t >> 6, lane = t & 63;
    const int q = lane >> 4, n = lane & 15;
    const int R0 = blockIdx.x * 16, row = R0 + n;
    const float v = s2[row] + BND, mhat = leaky(v);
    const float E1 = __expf(v - mhat), E2 = __expf(0.2f * v - mhat);
    const unsigned long long* arow = abits + (size_t)row * 64;

    f32x4 acc = {0.f, 0.f, 0.f, 0.f};
    float lsum = 0.f;
    const int jbeg = wv * 256;
    for (int j0 = jbeg; j0 < jbeg + 256; j0 += 64) {
        const unsigned long long a64 = arow[j0 >> 6];
        #pragma unroll
        for (int ch = 0; ch < 2; ++ch) {
            const int kb = ch * 32 + q * 8;
            const float4 f1a = *(const float4*)(F1 + j0 + kb);
            const float4 f1b = *(const float4*)(F1 + j0 + kb + 4);
            const float4 f2a = *(const float4*)(F2 + j0 + kb);
            const float4 f2b = *(const float4*)(F2 + j0 + kb + 4);
            const float F1v[8] = {f1a.x, f1a.y, f1a.z, f1a.w, f1b.x, f1b.y, f1b.z, f1b.w};
            const float F2v[8] = {f2a.x, f2a.y, f2a.z, f2a.w, f2b.x, f2b.y, f2b.z, f2b.w};
            const unsigned b8 = (unsigned)(a64 >> kb) & 0xffu;
            unsigned au[4];
            #pragma unroll
            for (int jp = 0; jp < 4; ++jp) {
                float p0 = fmaxf(E1 * F1v[2*jp],   E2 * F2v[2*jp]);
                float p1 = fmaxf(E1 * F1v[2*jp+1], E2 * F2v[2*jp+1]);
                p0 = __uint_as_float(__float_as_uint(p0) & bmask(b8, 2*jp));
                p1 = __uint_as_float(__float_as_uint(p1) & bmask(b8, 2*jp+1));
                lsum += p0 + p1;
                au[jp] = pkbf(p0, p1);
            }
            const bf16x8 af = mk8(au[0], au[1], au[2], au[3]);
            const bf16x8 bf = *(const bf16x8*)(f2bT + (size_t)n * NN + j0 + kb);
            acc = __builtin_amdgcn_mfma_f32_16x16x32_bf16(af, bf, acc, 0, 0, 0);
        }
    }
    lsum += __shfl_xor(lsum, 16, 64);
    lsum += __shfl_xor(lsum, 32, 64);
    #pragma unroll
    for (int i = 0; i < 4; ++i) cmb[wv][q * 4 + i][n] = acc[i];
    if (q == 0) lw[wv][n] = lsum;
    __syncthreads();

    if (t < 256) {
        const int r = t >> 4, c = t & 15;
        float tot = 0.f, lt = 0.f;
        #pragma unroll
        for (int w16 = 0; w16 < 16; ++w16) { tot += cmb[w16][r][c]; lt += lw[w16][r]; }
        float val = fmaxf(tot / lt + b2[c], 0.f);
        float mx = val;
        #pragma unroll
        for (int off = 1; off < 16; off <<= 1) mx = fmaxf(mx, __shfl_xor(mx, off, 64));
        const float e = __expf(val - mx);
        float se = e;
        #pragma unroll
        for (int off = 1; off < 16; off <<= 1) se += __shfl_xor(se, off, 64);
        out[(size_t)(R0 + r) * NCLS + c] = val - mx - __logf(se);
    }
}

// ---------------------------------------------------------------------------
extern "C" void kernel_launch(void* const* d_in, const int* in_sizes, int n_in,
                              void* d_out, int out_size, void* d_ws, size_t ws_size,
                              hipStream_t stream)
{
    const float* x   = (const float*)d_in[0];
    const int*   adj = (const int*)  d_in[1];
    const float* W1  = (const float*)d_in[2];
    const float* b1  = (const float*)d_in[3];
    const float* as1 = (const float*)d_in[4];
    const float* an1 = (const float*)d_in[5];
    const float* W2  = (const float*)d_in[6];
    const float* b2  = (const float*)d_in[7];
    const float* as2 = (const float*)d_in[8];
    const float* an2 = (const float*)d_in[9];
    float* out = (float*)d_out;

    char* ws = (char*)d_ws;
    unsigned long long* abits = (unsigned long long*)(ws);            // 2 MB
    unsigned short* f1bT  = (unsigned short*)(ws + (2u << 20));       // 4 MB
    unsigned short* hcatb = (unsigned short*)(ws + (6u << 20));       // 4 MB
    unsigned short* w1f   = (unsigned short*)(ws + (10u << 20));      // 512 KB
    char* ws2 = ws + (10u << 20) + (512u << 10);
    float* s1   = (float*)(ws2);                                      // 128 KB
    float* F1a  = (float*)(ws2 + (128u << 10));                       // 128 KB
    float* F2a  = (float*)(ws2 + (256u << 10));                       // 128 KB
    unsigned short* f2bT = (unsigned short*)(ws2 + (384u << 10));     // 128 KB
    float* s2   = (float*)(ws2 + (512u << 10));                       // 16 KB
    float* F1b  = (float*)(ws2 + (528u << 10));                       // 16 KB
    float* F2b  = (float*)(ws2 + (544u << 10));                       // 16 KB

    k_prep  <<<dim3(NN + 64),     256, 0, stream>>>(adj, abits, W1, w1f);
    k_feats1<<<dim3(NN / 64, H1), 256, 0, stream>>>(x, w1f, as1, an1, f1bT, s1, F1a, F2a);
    k_gat1  <<<dim3(NN / 32, H1), 512, 0, stream>>>(f1bT, s1, F1a, F2a, abits, b1, hcatb);
    k_feats2<<<dim3(NN / 32),     128, 0, stream>>>(hcatb, W2, as2, an2, f2bT, s2, F1b, F2b);
    k_gat2  <<<dim3(NN / 16),     1024, 0, stream>>>(f2bT, s2, F1b, F2b, abits, b2, out);
}

// Round 6
// 229.517 us; speedup vs baseline: 2.6095x; 1.2921x over previous
//
#include <hip/hip_runtime.h>

#define NN 4096
#define NFEAT 512
#define NHID 64
#define H1 8
#define NCLS 16
#define BND 40.0f   // static upper bound for nbmax (true ~13 layer1, ~0.5 layer2)

typedef short bf16x8 __attribute__((ext_vector_type(8)));
typedef float f32x4 __attribute__((ext_vector_type(4)));

__device__ __forceinline__ unsigned short f2bf(float f) {
    unsigned u = __float_as_uint(f);
    u += 0x7fffu + ((u >> 16) & 1u);          // RNE
    return (unsigned short)(u >> 16);
}
__device__ __forceinline__ float leaky(float v) { return fmaxf(v, 0.2f * v); }
// pack two fp32 -> dword of two bf16 (round-half-up, 3 instr per 2 values)
__device__ __forceinline__ unsigned pkbf(float lo, float hi) {
    return __builtin_amdgcn_perm(__float_as_uint(hi) + 0x8000u,
                                 __float_as_uint(lo) + 0x8000u, 0x07060302u);
}
__device__ __forceinline__ bf16x8 mk8(unsigned a, unsigned b, unsigned c, unsigned d) {
    union { unsigned u[4]; bf16x8 v; } cv;
    cv.u[0] = a; cv.u[1] = b; cv.u[2] = c; cv.u[3] = d; return cv.v;
}
// bit i of b -> 0x00000000 / 0xFFFFFFFF in 1-2 VALU (v_bfe_i32 width=1)
__device__ __forceinline__ unsigned bmask(unsigned b, int i) {
#if __has_builtin(__builtin_amdgcn_sbfe)
    return (unsigned)__builtin_amdgcn_sbfe((int)b, (unsigned)i, 1u);
#else
    return 0u - ((b >> i) & 1u);
#endif
}

// ---------------------------------------------------------------------------
// Dual-role: bx < 4096 -> pack adj row; else -> W1 -> MFMA-frag-major bf16.
// w1f element ((h*16+kg)*4+nt)*512 + lane*8 + e  =  W1[h][kg*32+q*8+e][nt*16+n]
// with lane = q*16+n. Consumer B-loads are then lane-contiguous (coalesced).
// ---------------------------------------------------------------------------
__global__ __launch_bounds__(256)
void k_prep(const int* __restrict__ adj, unsigned long long* __restrict__ bits,
            const float* __restrict__ W1, unsigned short* __restrict__ w1f)
{
    __shared__ float wt[64][65];
    const int t = threadIdx.x, bx = blockIdx.x;
    if (bx < NN) {
        const int wv = t >> 6, lane = t & 63;
        const int* ap = adj + (size_t)bx * NN;
        for (int w = wv; w < 64; w += 4) {
            unsigned long long m = __ballot(ap[w * 64 + lane] > 0);
            if (lane == 0) bits[(size_t)bx * 64 + w] = m;
        }
        return;
    }
    const int kt = (bx - NN) & 7, h = (bx - NN) >> 3;
    #pragma unroll
    for (int i = 0; i < 4; ++i) {
        const int f = t + 256 * i;
        const int r = f >> 4, c4 = f & 15;   // r = k_local, c4*4 = c
        const float4 v = *(const float4*)(W1 + ((size_t)(h * NFEAT) + kt * 64 + r) * NHID + c4 * 4);
        wt[r][c4 * 4 + 0] = v.x; wt[r][c4 * 4 + 1] = v.y;
        wt[r][c4 * 4 + 2] = v.z; wt[r][c4 * 4 + 3] = v.w;
    }
    __syncthreads();
    #pragma unroll
    for (int s = 0; s < 2; ++s) {
        const int o = t + s * 256;                   // octet id 0..511
        const int kg2 = o >> 8, rem = o & 255;
        const int nt = rem >> 6, lane2 = rem & 63;
        const int qq = lane2 >> 4, nn = lane2 & 15;
        const int kl = kg2 * 32 + qq * 8;            // k_local base
        const int c = nt * 16 + nn;
        uint4 w;
        w.x = pkbf(wt[kl + 0][c], wt[kl + 1][c]);
        w.y = pkbf(wt[kl + 2][c], wt[kl + 3][c]);
        w.z = pkbf(wt[kl + 4][c], wt[kl + 5][c]);
        w.w = pkbf(wt[kl + 6][c], wt[kl + 7][c]);
        *(uint4*)(w1f + (((size_t)h * 16 + kt * 2 + kg2) * 4 + nt) * 512 + lane2 * 8) = w;
    }
}

// ---------------------------------------------------------------------------
// feats1 = x @ W1 via MFMA -> f1t (TILE-MAJOR: f1t[((h*128+jt)*64+col)*32+jo],
// jt = j>>5, jo = j&31) + s1 + F1a/F2a. grid (64,8), 256 thr.
// Tile-major makes the consumer's per-iteration 4 KB B-tile contiguous, and
// each MFMA B-frag a coalesced 16 B/lane direct global load (R5 lesson:
// per-wave contiguity, not per-lane, is what coalescing needs).
// ---------------------------------------------------------------------------
__global__ __launch_bounds__(256)
void k_feats1(const float* __restrict__ x, const unsigned short* __restrict__ w1f,
              const float* __restrict__ as1, const float* __restrict__ an1,
              unsigned short* __restrict__ f1t, float* __restrict__ s1,
              float* __restrict__ F1a, float* __restrict__ F2a)
{
    const int t = threadIdx.x, wv = t >> 6, lane = t & 63;
    const int q = lane >> 4, n = lane & 15;
    const int h = blockIdx.y, R0 = blockIdx.x * 64;
    const int row = R0 + wv * 16 + n;
    const float* ap = x + (size_t)row * NFEAT;
    const unsigned short* wp = w1f + (size_t)h * 16 * 4 * 512 + lane * 8;
    f32x4 acc[4] = {{0.f,0.f,0.f,0.f},{0.f,0.f,0.f,0.f},{0.f,0.f,0.f,0.f},{0.f,0.f,0.f,0.f}};
    #pragma unroll 4
    for (int kg = 0; kg < 16; ++kg) {
        const float4 xa = *(const float4*)(ap + kg * 32 + q * 8);
        const float4 xb = *(const float4*)(ap + kg * 32 + q * 8 + 4);
        const bf16x8 af = mk8(pkbf(xa.x, xa.y), pkbf(xa.z, xa.w),
                              pkbf(xb.x, xb.y), pkbf(xb.z, xb.w));
        #pragma unroll
        for (int nt = 0; nt < 4; ++nt) {
            const bf16x8 bf = *(const bf16x8*)(wp + (size_t)(kg * 4 + nt) * 512);
            acc[nt] = __builtin_amdgcn_mfma_f32_16x16x32_bf16(af, bf, acc[nt], 0, 0, 0);
        }
    }
    {   // tile-major store: j = R0 + wv*16 + q*4 + i (i=0..3 contiguous in jo)
        const int jg = R0 + wv * 16 + q * 4;
        const int jt = jg >> 5, jo = jg & 31;
        #pragma unroll
        for (int nt = 0; nt < 4; ++nt) {
            uint2 w;
            w.x = pkbf(acc[nt][0], acc[nt][1]);
            w.y = pkbf(acc[nt][2], acc[nt][3]);
            *(uint2*)(f1t + (((size_t)h * 128 + jt) * 64 + nt * 16 + n) * 32 + jo) = w;
        }
    }
    float asv[4], anv[4];
    #pragma unroll
    for (int nt = 0; nt < 4; ++nt) {
        asv[nt] = as1[h * NHID + nt * 16 + n];
        anv[nt] = an1[h * NHID + nt * 16 + n];
    }
    #pragma unroll
    for (int i = 0; i < 4; ++i) {
        float ps = acc[0][i]*asv[0] + acc[1][i]*asv[1] + acc[2][i]*asv[2] + acc[3][i]*asv[3];
        float pn = acc[0][i]*anv[0] + acc[1][i]*anv[1] + acc[2][i]*anv[2] + acc[3][i]*anv[3];
        #pragma unroll
        for (int off = 8; off > 0; off >>= 1) {
            ps += __shfl_xor(ps, off, 64);
            pn += __shfl_xor(pn, off, 64);
        }
        if (n == 0) {
            const int idx = R0 + wv * 16 + q * 4 + i;
            s1[h * NN + idx] = ps;
            F1a[h * NN + idx] = __expf(pn - BND);
            F2a[h * NN + idx] = __expf(0.2f * (pn - BND));
        }
    }
}

// ---------------------------------------------------------------------------
// Layer-1 aggregation, LDS-free main loop (tile-major B direct from global).
// Grid 1024 x 512 thr; h = bid&7 (XCD-pinned head -> per-XCD L2 hot set =
// one 512 KB panel), R0 = (bid>>3)*32. Wave wv owns j-stream [wv*512,+512):
// 16 iters x 32-j tile. B-frag = coalesced 16 B/lane global load (1 KB/instr
// contiguous), register-double-buffered one iter ahead (T14). Zero main-loop
// barriers, zero main-loop LDS. (512,4) -> 64-VGPR cap (R5: body fits at 52).
// Block-level panel reuse preserved (R1 lesson). Epilogue LDS only (35 KB ->
// 4 blocks/CU = 32 waves/CU).
// ---------------------------------------------------------------------------
__global__ __launch_bounds__(512, 4)
void k_gat1(const unsigned short* __restrict__ f1t, const float* __restrict__ s1,
            const float* __restrict__ F1, const float* __restrict__ F2,
            const unsigned long long* __restrict__ abits, const float* __restrict__ b1,
            unsigned short* __restrict__ hcatb)
{
    __shared__ __align__(16) float cmbf[8][16][68];   // 34816 B
    __shared__ float lwf[8][16];                      //   512 B

    const int t = threadIdx.x, wv = t >> 6, lane = t & 63;
    const int q = lane >> 4, n = lane & 15;
    const int bid = blockIdx.x;
    const int h = bid & 7, R0 = (bid >> 3) * 32;
    const int rowA = R0 + n, rowB = R0 + 16 + n;

    const float vA = s1[h * NN + rowA] + BND, mhA = leaky(vA);
    const float vB = s1[h * NN + rowB] + BND, mhB = leaky(vB);
    const float E1A = __expf(vA - mhA), E2A = __expf(0.2f * vA - mhA);
    const float E1B = __expf(vB - mhB), E2B = __expf(0.2f * vB - mhB);

    const unsigned* arowA32 = (const unsigned*)abits + (size_t)rowA * 128 + wv * 16;
    const unsigned* arowB32 = (const unsigned*)abits + (size_t)rowB * 128 + wv * 16;
    const float* F1p = F1 + (size_t)h * NN + wv * 512;
    const float* F2p = F2 + (size_t)h * NN + wv * 512;

    // B-frag base for this lane: tile (wv*16 + it), col nt*16+n, j-offset q*8
    const unsigned short* vbase = f1t + ((size_t)h * 128 + wv * 16) * 2048 + n * 32 + q * 8;

    f32x4 accA[4] = {{0.f,0.f,0.f,0.f},{0.f,0.f,0.f,0.f},{0.f,0.f,0.f,0.f},{0.f,0.f,0.f,0.f}};
    f32x4 accB[4] = {{0.f,0.f,0.f,0.f},{0.f,0.f,0.f,0.f},{0.f,0.f,0.f,0.f},{0.f,0.f,0.f,0.f}};
    float lsA = 0.f, lsB = 0.f;

    bf16x8 vb[4];
    #pragma unroll
    for (int nt = 0; nt < 4; ++nt) vb[nt] = *(const bf16x8*)(vbase + nt * 512);

    #pragma unroll 2
    for (int it = 0; it < 16; ++it) {
        bf16x8 nb[4];
        if (it < 15) {           // prefetch next tile's B-frags (hides under VALU)
            const unsigned short* p = vbase + (size_t)(it + 1) * 2048;
            #pragma unroll
            for (int nt = 0; nt < 4; ++nt) nb[nt] = *(const bf16x8*)(p + nt * 512);
        }
        const int j0 = it * 32, kb = q * 8;
        const unsigned aA = arowA32[it], aB = arowB32[it];
        const float4 f1a = *(const float4*)(F1p + j0 + kb);
        const float4 f1b = *(const float4*)(F1p + j0 + kb + 4);
        const float4 f2a = *(const float4*)(F2p + j0 + kb);
        const float4 f2b = *(const float4*)(F2p + j0 + kb + 4);
        const float F1v[8] = {f1a.x, f1a.y, f1a.z, f1a.w, f1b.x, f1b.y, f1b.z, f1b.w};
        const float F2v[8] = {f2a.x, f2a.y, f2a.z, f2a.w, f2b.x, f2b.y, f2b.z, f2b.w};
        const unsigned bA8 = (aA >> kb) & 0xffu;
        const unsigned bB8 = (aB >> kb) & 0xffu;
        unsigned uA[4], uB[4];
        #pragma unroll
        for (int jp = 0; jp < 4; ++jp) {
            float a0 = fmaxf(E1A * F1v[2*jp],   E2A * F2v[2*jp]);
            float a1 = fmaxf(E1A * F1v[2*jp+1], E2A * F2v[2*jp+1]);
            a0 = __uint_as_float(__float_as_uint(a0) & bmask(bA8, 2*jp));
            a1 = __uint_as_float(__float_as_uint(a1) & bmask(bA8, 2*jp+1));
            lsA += a0 + a1;
            uA[jp] = pkbf(a0, a1);
            float b0  = fmaxf(E1B * F1v[2*jp],   E2B * F2v[2*jp]);
            float b1v = fmaxf(E1B * F1v[2*jp+1], E2B * F2v[2*jp+1]);
            b0  = __uint_as_float(__float_as_uint(b0)  & bmask(bB8, 2*jp));
            b1v = __uint_as_float(__float_as_uint(b1v) & bmask(bB8, 2*jp+1));
            lsB += b0 + b1v;
            uB[jp] = pkbf(b0, b1v);
        }
        const bf16x8 afA = mk8(uA[0], uA[1], uA[2], uA[3]);
        const bf16x8 afB = mk8(uB[0], uB[1], uB[2], uB[3]);
        #pragma unroll
        for (int nt = 0; nt < 4; ++nt) {
            accA[nt] = __builtin_amdgcn_mfma_f32_16x16x32_bf16(afA, vb[nt], accA[nt], 0, 0, 0);
            accB[nt] = __builtin_amdgcn_mfma_f32_16x16x32_bf16(afB, vb[nt], accB[nt], 0, 0, 0);
        }
        #pragma unroll
        for (int nt = 0; nt < 4; ++nt) vb[nt] = nb[nt];
    }

    lsA += __shfl_xor(lsA, 16, 64); lsA += __shfl_xor(lsA, 32, 64);
    lsB += __shfl_xor(lsB, 16, 64); lsB += __shfl_xor(lsB, 32, 64);

    // ---- pass A: rows R0 .. R0+15 ----
    #pragma unroll
    for (int nt = 0; nt < 4; ++nt)
        #pragma unroll
        for (int i = 0; i < 4; ++i)
            cmbf[wv][q * 4 + i][nt * 16 + n] = accA[nt][i];
    if (q == 0) lwf[wv][n] = lsA;
    __syncthreads();
    {
        const int r = t >> 5, c0 = (t & 31) * 2;
        float t0 = 0.f, t1 = 0.f, lt = 0.f;
        #pragma unroll
        for (int jj = 0; jj < 8; ++jj) {
            const float2 v = *(const float2*)&cmbf[jj][r][c0];
            t0 += v.x; t1 += v.y;
            lt += lwf[jj][r];
        }
        const float o0 = fmaxf(t0 / lt + b1[h * NHID + c0], 0.f);     // relu; elu(x>=0)=x
        const float o1 = fmaxf(t1 / lt + b1[h * NHID + c0 + 1], 0.f);
        *(unsigned*)(hcatb + (size_t)(R0 + r) * (H1 * NHID) + h * NHID + c0) = pkbf(o0, o1);
    }
    __syncthreads();

    // ---- pass B: rows R0+16 .. R0+31 ----
    #pragma unroll
    for (int nt = 0; nt < 4; ++nt)
        #pragma unroll
        for (int i = 0; i < 4; ++i)
            cmbf[wv][q * 4 + i][nt * 16 + n] = accB[nt][i];
    if (q == 0) lwf[wv][n] = lsB;
    __syncthreads();
    {
        const int r = t >> 5, c0 = (t & 31) * 2;
        float t0 = 0.f, t1 = 0.f, lt = 0.f;
        #pragma unroll
        for (int jj = 0; jj < 8; ++jj) {
            const float2 v = *(const float2*)&cmbf[jj][r][c0];
            t0 += v.x; t1 += v.y;
            lt += lwf[jj][r];
        }
        const float o0 = fmaxf(t0 / lt + b1[h * NHID + c0], 0.f);
        const float o1 = fmaxf(t1 / lt + b1[h * NHID + c0 + 1], 0.f);
        *(unsigned*)(hcatb + (size_t)(R0 + 16 + r) * (H1 * NHID) + h * NHID + c0) = pkbf(o0, o1);
    }
}

// ---------------------------------------------------------------------------
// feats2 = hcatb @ W2 (W2 -> bf16 LDS transpose in-kernel) -> f2bT + s2 +
// F1b/F2b. grid 128, 128 thr.
// ---------------------------------------------------------------------------
__global__ __launch_bounds__(128)
void k_feats2(const unsigned short* __restrict__ hcatb, const float* __restrict__ W2,
              const float* __restrict__ as2, const float* __restrict__ an2,
              unsigned short* __restrict__ f2bT, float* __restrict__ s2,
              float* __restrict__ F1b, float* __restrict__ F2b)
{
    __shared__ __align__(16) unsigned short w2T[NCLS][520];
    const int t = threadIdx.x, wv = t >> 6, lane = t & 63;
    const int q = lane >> 4, n = lane & 15;
    #pragma unroll
    for (int i = 0; i < 16; ++i) {
        const int f4 = t + 128 * i;
        const float4 v = ((const float4*)W2)[f4];
        const int k = f4 >> 2, c0 = (f4 & 3) * 4;
        w2T[c0 + 0][k] = f2bf(v.x); w2T[c0 + 1][k] = f2bf(v.y);
        w2T[c0 + 2][k] = f2bf(v.z); w2T[c0 + 3][k] = f2bf(v.w);
    }
    __syncthreads();

    const int R0 = blockIdx.x * 32;
    const int row = R0 + wv * 16 + n;
    const unsigned short* ap = hcatb + (size_t)row * NFEAT;
    f32x4 acc = {0.f, 0.f, 0.f, 0.f};
    #pragma unroll 4
    for (int k0 = 0; k0 < NFEAT; k0 += 32) {
        const bf16x8 af = *(const bf16x8*)(ap + k0 + q * 8);
        const bf16x8 bf = *(const bf16x8*)&w2T[n][k0 + q * 8];
        acc = __builtin_amdgcn_mfma_f32_16x16x32_bf16(af, bf, acc, 0, 0, 0);
    }
    uint2 w;
    w.x = pkbf(acc[0], acc[1]);
    w.y = pkbf(acc[2], acc[3]);
    *(uint2*)(f2bT + (size_t)n * NN + R0 + wv * 16 + q * 4) = w;
    const float asv = as2[n], anv = an2[n];
    #pragma unroll
    for (int i = 0; i < 4; ++i) {
        float ps = acc[i] * asv, pn = acc[i] * anv;
        #pragma unroll
        for (int off = 8; off > 0; off >>= 1) {
            ps += __shfl_xor(ps, off, 64);
            pn += __shfl_xor(pn, off, 64);
        }
        if (n == 0) {
            const int idx = R0 + wv * 16 + q * 4 + i;
            s2[idx] = ps;
            F1b[idx] = __expf(pn - BND);
            F2b[idx] = __expf(0.2f * (pn - BND));
        }
    }
}

// ---------------------------------------------------------------------------
// Layer-2 aggregation + relu + log_softmax. 1024 thr = 16 wave j-sixteenths.
// ---------------------------------------------------------------------------
__global__ __launch_bounds__(1024)
void k_gat2(const unsigned short* __restrict__ f2bT, const float* __restrict__ s2,
            const float* __restrict__ F1, const float* __restrict__ F2,
            const unsigned long long* __restrict__ abits, const float* __restrict__ b2,
            float* __restrict__ out)
{
    __shared__ float cmb[16][16][17];
    __shared__ float lw[16][16];
    const int t = threadIdx.x, wv = t >> 6, lane = t & 63;
    const int q = lane >> 4, n = lane & 15;
    const int R0 = blockIdx.x * 16, row = R0 + n;
    const float v = s2[row] + BND, mhat = leaky(v);
    const float E1 = __expf(v - mhat), E2 = __expf(0.2f * v - mhat);
    const unsigned long long* arow = abits + (size_t)row * 64;

    f32x4 acc = {0.f, 0.f, 0.f, 0.f};
    float lsum = 0.f;
    const int jbeg = wv * 256;
    for (int j0 = jbeg; j0 < jbeg + 256; j0 += 64) {
        const unsigned long long a64 = arow[j0 >> 6];
        #pragma unroll
        for (int ch = 0; ch < 2; ++ch) {
            const int kb = ch * 32 + q * 8;
            const float4 f1a = *(const float4*)(F1 + j0 + kb);
            const float4 f1b = *(const float4*)(F1 + j0 + kb + 4);
            const float4 f2a = *(const float4*)(F2 + j0 + kb);
            const float4 f2b = *(const float4*)(F2 + j0 + kb + 4);
            const float F1v[8] = {f1a.x, f1a.y, f1a.z, f1a.w, f1b.x, f1b.y, f1b.z, f1b.w};
            const float F2v[8] = {f2a.x, f2a.y, f2a.z, f2a.w, f2b.x, f2b.y, f2b.z, f2b.w};
            const unsigned b8 = (unsigned)(a64 >> kb) & 0xffu;
            unsigned au[4];
            #pragma unroll
            for (int jp = 0; jp < 4; ++jp) {
                float p0 = fmaxf(E1 * F1v[2*jp],   E2 * F2v[2*jp]);
                float p1 = fmaxf(E1 * F1v[2*jp+1], E2 * F2v[2*jp+1]);
                p0 = __uint_as_float(__float_as_uint(p0) & bmask(b8, 2*jp));
                p1 = __uint_as_float(__float_as_uint(p1) & bmask(b8, 2*jp+1));
                lsum += p0 + p1;
                au[jp] = pkbf(p0, p1);
            }
            const bf16x8 af = mk8(au[0], au[1], au[2], au[3]);
            const bf16x8 bf = *(const bf16x8*)(f2bT + (size_t)n * NN + j0 + kb);
            acc = __builtin_amdgcn_mfma_f32_16x16x32_bf16(af, bf, acc, 0, 0, 0);
        }
    }
    lsum += __shfl_xor(lsum, 16, 64);
    lsum += __shfl_xor(lsum, 32, 64);
    #pragma unroll
    for (int i = 0; i < 4; ++i) cmb[wv][q * 4 + i][n] = acc[i];
    if (q == 0) lw[wv][n] = lsum;
    __syncthreads();

    if (t < 256) {
        const int r = t >> 4, c = t & 15;
        float tot = 0.f, lt = 0.f;
        #pragma unroll
        for (int w16 = 0; w16 < 16; ++w16) { tot += cmb[w16][r][c]; lt += lw[w16][r]; }
        float val = fmaxf(tot / lt + b2[c], 0.f);
        float mx = val;
        #pragma unroll
        for (int off = 1; off < 16; off <<= 1) mx = fmaxf(mx, __shfl_xor(mx, off, 64));
        const float e = __expf(val - mx);
        float se = e;
        #pragma unroll
        for (int off = 1; off < 16; off <<= 1) se += __shfl_xor(se, off, 64);
        out[(size_t)(R0 + r) * NCLS + c] = val - mx - __logf(se);
    }
}

// ---------------------------------------------------------------------------
extern "C" void kernel_launch(void* const* d_in, const int* in_sizes, int n_in,
                              void* d_out, int out_size, void* d_ws, size_t ws_size,
                              hipStream_t stream)
{
    const float* x   = (const float*)d_in[0];
    const int*   adj = (const int*)  d_in[1];
    const float* W1  = (const float*)d_in[2];
    const float* b1  = (const float*)d_in[3];
    const float* as1 = (const float*)d_in[4];
    const float* an1 = (const float*)d_in[5];
    const float* W2  = (const float*)d_in[6];
    const float* b2  = (const float*)d_in[7];
    const float* as2 = (const float*)d_in[8];
    const float* an2 = (const float*)d_in[9];
    float* out = (float*)d_out;

    char* ws = (char*)d_ws;
    unsigned long long* abits = (unsigned long long*)(ws);            // 2 MB
    unsigned short* f1t   = (unsigned short*)(ws + (2u << 20));       // 4 MB (tile-major)
    unsigned short* hcatb = (unsigned short*)(ws + (6u << 20));       // 4 MB
    unsigned short* w1f   = (unsigned short*)(ws + (10u << 20));      // 512 KB
    char* ws2 = ws + (10u << 20) + (512u << 10);
    float* s1   = (float*)(ws2);                                      // 128 KB
    float* F1a  = (float*)(ws2 + (128u << 10));                       // 128 KB
    float* F2a  = (float*)(ws2 + (256u << 10));                       // 128 KB
    unsigned short* f2bT = (unsigned short*)(ws2 + (384u << 10));     // 128 KB
    float* s2   = (float*)(ws2 + (512u << 10));                       // 16 KB
    float* F1b  = (float*)(ws2 + (528u << 10));                       // 16 KB
    float* F2b  = (float*)(ws2 + (544u << 10));                       // 16 KB

    k_prep  <<<dim3(NN + 64),     256, 0, stream>>>(adj, abits, W1, w1f);
    k_feats1<<<dim3(NN / 64, H1), 256, 0, stream>>>(x, w1f, as1, an1, f1t, s1, F1a, F2a);
    k_gat1  <<<dim3(NN / 32 * H1), 512, 0, stream>>>(f1t, s1, F1a, F2a, abits, b1, hcatb);
    k_feats2<<<dim3(NN / 32),     128, 0, stream>>>(hcatb, W2, as2, an2, f2bT, s2, F1b, F2b);
    k_gat2  <<<dim3(NN / 16),     1024, 0, stream>>>(f2bT, s2, F1b, F2b, abits, b2, out);
}

// Round 7
// 213.008 us; speedup vs baseline: 2.8117x; 1.0775x over previous
//
#include <hip/hip_runtime.h>

#define NN 4096
#define NFEAT 512
#define NHID 64
#define H1 8
#define NCLS 16
#define BND 40.0f   // static upper bound for nbmax (true ~13 layer1, ~0.5 layer2)

typedef short bf16x8 __attribute__((ext_vector_type(8)));
typedef float f32x4 __attribute__((ext_vector_type(4)));

__device__ __forceinline__ unsigned short f2bf(float f) {
    unsigned u = __float_as_uint(f);
    u += 0x7fffu + ((u >> 16) & 1u);          // RNE
    return (unsigned short)(u >> 16);
}
__device__ __forceinline__ float leaky(float v) { return fmaxf(v, 0.2f * v); }
// pack two fp32 -> dword of two bf16 (round-half-up, 3 instr per 2 values)
__device__ __forceinline__ unsigned pkbf(float lo, float hi) {
    return __builtin_amdgcn_perm(__float_as_uint(hi) + 0x8000u,
                                 __float_as_uint(lo) + 0x8000u, 0x07060302u);
}
__device__ __forceinline__ bf16x8 mk8(unsigned a, unsigned b, unsigned c, unsigned d) {
    union { unsigned u[4]; bf16x8 v; } cv;
    cv.u[0] = a; cv.u[1] = b; cv.u[2] = c; cv.u[3] = d; return cv.v;
}
// bit i of b -> 0x00000000 / 0xFFFFFFFF in 1-2 VALU (v_bfe_i32 width=1)
__device__ __forceinline__ unsigned bmask(unsigned b, int i) {
#if __has_builtin(__builtin_amdgcn_sbfe)
    return (unsigned)__builtin_amdgcn_sbfe((int)b, (unsigned)i, 1u);
#else
    return 0u - ((b >> i) & 1u);
#endif
}

// ---------------------------------------------------------------------------
// Dual-role: bx < 4096 -> pack adj row; else -> W1 -> MFMA-frag-major bf16.
// ---------------------------------------------------------------------------
__global__ __launch_bounds__(256)
void k_prep(const int* __restrict__ adj, unsigned long long* __restrict__ bits,
            const float* __restrict__ W1, unsigned short* __restrict__ w1f)
{
    __shared__ float wt[64][65];
    const int t = threadIdx.x, bx = blockIdx.x;
    if (bx < NN) {
        const int wv = t >> 6, lane = t & 63;
        const int* ap = adj + (size_t)bx * NN;
        for (int w = wv; w < 64; w += 4) {
            unsigned long long m = __ballot(ap[w * 64 + lane] > 0);
            if (lane == 0) bits[(size_t)bx * 64 + w] = m;
        }
        return;
    }
    const int kt = (bx - NN) & 7, h = (bx - NN) >> 3;
    #pragma unroll
    for (int i = 0; i < 4; ++i) {
        const int f = t + 256 * i;
        const int r = f >> 4, c4 = f & 15;   // r = k_local, c4*4 = c
        const float4 v = *(const float4*)(W1 + ((size_t)(h * NFEAT) + kt * 64 + r) * NHID + c4 * 4);
        wt[r][c4 * 4 + 0] = v.x; wt[r][c4 * 4 + 1] = v.y;
        wt[r][c4 * 4 + 2] = v.z; wt[r][c4 * 4 + 3] = v.w;
    }
    __syncthreads();
    #pragma unroll
    for (int s = 0; s < 2; ++s) {
        const int o = t + s * 256;                   // octet id 0..511
        const int kg2 = o >> 8, rem = o & 255;
        const int nt = rem >> 6, lane2 = rem & 63;
        const int qq = lane2 >> 4, nn = lane2 & 15;
        const int kl = kg2 * 32 + qq * 8;            // k_local base
        const int c = nt * 16 + nn;
        uint4 w;
        w.x = pkbf(wt[kl + 0][c], wt[kl + 1][c]);
        w.y = pkbf(wt[kl + 2][c], wt[kl + 3][c]);
        w.z = pkbf(wt[kl + 4][c], wt[kl + 5][c]);
        w.w = pkbf(wt[kl + 6][c], wt[kl + 7][c]);
        *(uint4*)(w1f + (((size_t)h * 16 + kt * 2 + kg2) * 4 + nt) * 512 + lane2 * 8) = w;
    }
}

// ---------------------------------------------------------------------------
// feats1 = x @ W1 via MFMA -> f1t (TILE-MAJOR: f1t[((h*128+jt)*64+col)*32+jo])
// + s1 + F1a/F2a. grid (64,8), 256 thr. (R6: proven — FETCH 10.5 MB, 0 bank
// conflicts, coalesced 1 KB/instr consumer loads.)
// ---------------------------------------------------------------------------
__global__ __launch_bounds__(256)
void k_feats1(const float* __restrict__ x, const unsigned short* __restrict__ w1f,
              const float* __restrict__ as1, const float* __restrict__ an1,
              unsigned short* __restrict__ f1t, float* __restrict__ s1,
              float* __restrict__ F1a, float* __restrict__ F2a)
{
    const int t = threadIdx.x, wv = t >> 6, lane = t & 63;
    const int q = lane >> 4, n = lane & 15;
    const int h = blockIdx.y, R0 = blockIdx.x * 64;
    const int row = R0 + wv * 16 + n;
    const float* ap = x + (size_t)row * NFEAT;
    const unsigned short* wp = w1f + (size_t)h * 16 * 4 * 512 + lane * 8;
    f32x4 acc[4] = {{0.f,0.f,0.f,0.f},{0.f,0.f,0.f,0.f},{0.f,0.f,0.f,0.f},{0.f,0.f,0.f,0.f}};
    #pragma unroll 4
    for (int kg = 0; kg < 16; ++kg) {
        const float4 xa = *(const float4*)(ap + kg * 32 + q * 8);
        const float4 xb = *(const float4*)(ap + kg * 32 + q * 8 + 4);
        const bf16x8 af = mk8(pkbf(xa.x, xa.y), pkbf(xa.z, xa.w),
                              pkbf(xb.x, xb.y), pkbf(xb.z, xb.w));
        #pragma unroll
        for (int nt = 0; nt < 4; ++nt) {
            const bf16x8 bf = *(const bf16x8*)(wp + (size_t)(kg * 4 + nt) * 512);
            acc[nt] = __builtin_amdgcn_mfma_f32_16x16x32_bf16(af, bf, acc[nt], 0, 0, 0);
        }
    }
    {   // tile-major store: j = R0 + wv*16 + q*4 + i (i=0..3 contiguous in jo)
        const int jg = R0 + wv * 16 + q * 4;
        const int jt = jg >> 5, jo = jg & 31;
        #pragma unroll
        for (int nt = 0; nt < 4; ++nt) {
            uint2 w;
            w.x = pkbf(acc[nt][0], acc[nt][1]);
            w.y = pkbf(acc[nt][2], acc[nt][3]);
            *(uint2*)(f1t + (((size_t)h * 128 + jt) * 64 + nt * 16 + n) * 32 + jo) = w;
        }
    }
    float asv[4], anv[4];
    #pragma unroll
    for (int nt = 0; nt < 4; ++nt) {
        asv[nt] = as1[h * NHID + nt * 16 + n];
        anv[nt] = an1[h * NHID + nt * 16 + n];
    }
    #pragma unroll
    for (int i = 0; i < 4; ++i) {
        float ps = acc[0][i]*asv[0] + acc[1][i]*asv[1] + acc[2][i]*asv[2] + acc[3][i]*asv[3];
        float pn = acc[0][i]*anv[0] + acc[1][i]*anv[1] + acc[2][i]*anv[2] + acc[3][i]*anv[3];
        #pragma unroll
        for (int off = 8; off > 0; off >>= 1) {
            ps += __shfl_xor(ps, off, 64);
            pn += __shfl_xor(pn, off, 64);
        }
        if (n == 0) {
            const int idx = R0 + wv * 16 + q * 4 + i;
            s1[h * NN + idx] = ps;
            F1a[h * NN + idx] = __expf(pn - BND);
            F2a[h * NN + idx] = __expf(0.2f * (pn - BND));
        }
    }
}

// ---------------------------------------------------------------------------
// Layer-1 aggregation. R6 structure (LDS-free B path, tile-major, XCD-pinned
// h = bid&7) + R7 fix: F1/F2 staged ONCE into per-wave-private LDS (4 KB/wave,
// broadcast-read conflict-free) -- R6 PMC showed the 48 us stall = same-iter
// F loads from L2 (~200cy; L1 thrashed by the 512 KB B-panel stream). Adj
// words prefetched one iter ahead. Still zero main-loop barriers. VALU-issue
// floor measured ~35 us (R0 and R6 both); this targets the stall component.
// ---------------------------------------------------------------------------
__global__ __launch_bounds__(512, 4)
void k_gat1(const unsigned short* __restrict__ f1t, const float* __restrict__ s1,
            const float* __restrict__ F1, const float* __restrict__ F2,
            const unsigned long long* __restrict__ abits, const float* __restrict__ b1,
            unsigned short* __restrict__ hcatb)
{
    __shared__ __align__(16) char smem[35328];        // fLds 32 KB | epi 34.5 KB
    float* fLds = (float*)smem;                       // [wv][1024]: F1[512],F2[512]

    const int t = threadIdx.x, wv = t >> 6, lane = t & 63;
    const int q = lane >> 4, n = lane & 15;
    const int bid = blockIdx.x;
    const int h = bid & 7, R0 = (bid >> 3) * 32;
    const int rowA = R0 + n, rowB = R0 + 16 + n;

    const float vA = s1[h * NN + rowA] + BND, mhA = leaky(vA);
    const float vB = s1[h * NN + rowB] + BND, mhB = leaky(vB);
    const float E1A = __expf(vA - mhA), E2A = __expf(0.2f * vA - mhA);
    const float E1B = __expf(vB - mhB), E2B = __expf(0.2f * vB - mhB);

    const unsigned* arowA32 = (const unsigned*)abits + (size_t)rowA * 128 + wv * 16;
    const unsigned* arowB32 = (const unsigned*)abits + (size_t)rowB * 128 + wv * 16;
    const float* F1p = F1 + (size_t)h * NN + wv * 512;
    const float* F2p = F2 + (size_t)h * NN + wv * 512;

    float* myF = fLds + wv * 1024;
    {   // one-time F stage: 2x float4 per array per lane, coalesced
        #pragma unroll
        for (int r = 0; r < 2; ++r) {
            *(float4*)(myF + r * 256 + lane * 4)       = *(const float4*)(F1p + r * 256 + lane * 4);
            *(float4*)(myF + 512 + r * 256 + lane * 4) = *(const float4*)(F2p + r * 256 + lane * 4);
        }
    }   // private slice: no barrier needed (per-wave DS ordering)

    // B-frag base for this lane: tile (wv*16 + it), col nt*16+n, j-offset q*8
    const unsigned short* vbase = f1t + ((size_t)h * 128 + wv * 16) * 2048 + n * 32 + q * 8;

    f32x4 accA[4] = {{0.f,0.f,0.f,0.f},{0.f,0.f,0.f,0.f},{0.f,0.f,0.f,0.f},{0.f,0.f,0.f,0.f}};
    f32x4 accB[4] = {{0.f,0.f,0.f,0.f},{0.f,0.f,0.f,0.f},{0.f,0.f,0.f,0.f},{0.f,0.f,0.f,0.f}};
    float lsA = 0.f, lsB = 0.f;

    bf16x8 vb[4];
    #pragma unroll
    for (int nt = 0; nt < 4; ++nt) vb[nt] = *(const bf16x8*)(vbase + nt * 512);
    unsigned aA = arowA32[0], aB = arowB32[0];

    #pragma unroll 2
    for (int it = 0; it < 16; ++it) {
        bf16x8 nb[4];
        unsigned aAn, aBn;
        if (it < 15) {           // prefetch next tile's B-frags + adj words
            const unsigned short* p = vbase + (size_t)(it + 1) * 2048;
            #pragma unroll
            for (int nt = 0; nt < 4; ++nt) nb[nt] = *(const bf16x8*)(p + nt * 512);
            aAn = arowA32[it + 1]; aBn = arowB32[it + 1];
        }
        const int j0 = it * 32, kb = q * 8;
        const float4 f1a = *(const float4*)(myF + j0 + kb);
        const float4 f1b = *(const float4*)(myF + j0 + kb + 4);
        const float4 f2a = *(const float4*)(myF + 512 + j0 + kb);
        const float4 f2b = *(const float4*)(myF + 512 + j0 + kb + 4);
        const float F1v[8] = {f1a.x, f1a.y, f1a.z, f1a.w, f1b.x, f1b.y, f1b.z, f1b.w};
        const float F2v[8] = {f2a.x, f2a.y, f2a.z, f2a.w, f2b.x, f2b.y, f2b.z, f2b.w};
        const unsigned bA8 = (aA >> kb) & 0xffu;
        const unsigned bB8 = (aB >> kb) & 0xffu;
        unsigned uA[4], uB[4];
        #pragma unroll
        for (int jp = 0; jp < 4; ++jp) {
            float a0 = fmaxf(E1A * F1v[2*jp],   E2A * F2v[2*jp]);
            float a1 = fmaxf(E1A * F1v[2*jp+1], E2A * F2v[2*jp+1]);
            a0 = __uint_as_float(__float_as_uint(a0) & bmask(bA8, 2*jp));
            a1 = __uint_as_float(__float_as_uint(a1) & bmask(bA8, 2*jp+1));
            lsA += a0 + a1;
            uA[jp] = pkbf(a0, a1);
            float b0  = fmaxf(E1B * F1v[2*jp],   E2B * F2v[2*jp]);
            float b1v = fmaxf(E1B * F1v[2*jp+1], E2B * F2v[2*jp+1]);
            b0  = __uint_as_float(__float_as_uint(b0)  & bmask(bB8, 2*jp));
            b1v = __uint_as_float(__float_as_uint(b1v) & bmask(bB8, 2*jp+1));
            lsB += b0 + b1v;
            uB[jp] = pkbf(b0, b1v);
        }
        const bf16x8 afA = mk8(uA[0], uA[1], uA[2], uA[3]);
        const bf16x8 afB = mk8(uB[0], uB[1], uB[2], uB[3]);
        #pragma unroll
        for (int nt = 0; nt < 4; ++nt) {
            accA[nt] = __builtin_amdgcn_mfma_f32_16x16x32_bf16(afA, vb[nt], accA[nt], 0, 0, 0);
            accB[nt] = __builtin_amdgcn_mfma_f32_16x16x32_bf16(afB, vb[nt], accB[nt], 0, 0, 0);
        }
        #pragma unroll
        for (int nt = 0; nt < 4; ++nt) vb[nt] = nb[nt];
        aA = aAn; aB = aBn;
    }

    lsA += __shfl_xor(lsA, 16, 64); lsA += __shfl_xor(lsA, 32, 64);
    lsB += __shfl_xor(lsB, 16, 64); lsB += __shfl_xor(lsB, 32, 64);

    __syncthreads();             // fLds dead; epilogue overlays the same smem

    float (*cmbf)[16][68] = (float (*)[16][68])smem;  // [8][16][68] = 34816 B
    float (*lwf)[16] = (float (*)[16])(smem + 8 * 16 * 68 * 4);

    // ---- pass A: rows R0 .. R0+15 ----
    #pragma unroll
    for (int nt = 0; nt < 4; ++nt)
        #pragma unroll
        for (int i = 0; i < 4; ++i)
            cmbf[wv][q * 4 + i][nt * 16 + n] = accA[nt][i];
    if (q == 0) lwf[wv][n] = lsA;
    __syncthreads();
    {
        const int r = t >> 5, c0 = (t & 31) * 2;
        float t0 = 0.f, t1 = 0.f, lt = 0.f;
        #pragma unroll
        for (int jj = 0; jj < 8; ++jj) {
            const float2 v = *(const float2*)&cmbf[jj][r][c0];
            t0 += v.x; t1 += v.y;
            lt += lwf[jj][r];
        }
        const float o0 = fmaxf(t0 / lt + b1[h * NHID + c0], 0.f);     // relu; elu(x>=0)=x
        const float o1 = fmaxf(t1 / lt + b1[h * NHID + c0 + 1], 0.f);
        *(unsigned*)(hcatb + (size_t)(R0 + r) * (H1 * NHID) + h * NHID + c0) = pkbf(o0, o1);
    }
    __syncthreads();

    // ---- pass B: rows R0+16 .. R0+31 ----
    #pragma unroll
    for (int nt = 0; nt < 4; ++nt)
        #pragma unroll
        for (int i = 0; i < 4; ++i)
            cmbf[wv][q * 4 + i][nt * 16 + n] = accB[nt][i];
    if (q == 0) lwf[wv][n] = lsB;
    __syncthreads();
    {
        const int r = t >> 5, c0 = (t & 31) * 2;
        float t0 = 0.f, t1 = 0.f, lt = 0.f;
        #pragma unroll
        for (int jj = 0; jj < 8; ++jj) {
            const float2 v = *(const float2*)&cmbf[jj][r][c0];
            t0 += v.x; t1 += v.y;
            lt += lwf[jj][r];
        }
        const float o0 = fmaxf(t0 / lt + b1[h * NHID + c0], 0.f);
        const float o1 = fmaxf(t1 / lt + b1[h * NHID + c0 + 1], 0.f);
        *(unsigned*)(hcatb + (size_t)(R0 + 16 + r) * (H1 * NHID) + h * NHID + c0) = pkbf(o0, o1);
    }
}

// ---------------------------------------------------------------------------
// feats2 = hcatb @ W2 -> f2t (TILE-MAJOR, mirrors f1t: f2t[(jt*16+col)*32+jo])
// + s2 + F1b/F2b. grid 128, 128 thr.
// ---------------------------------------------------------------------------
__global__ __launch_bounds__(128)
void k_feats2(const unsigned short* __restrict__ hcatb, const float* __restrict__ W2,
              const float* __restrict__ as2, const float* __restrict__ an2,
              unsigned short* __restrict__ f2t, float* __restrict__ s2,
              float* __restrict__ F1b, float* __restrict__ F2b)
{
    __shared__ __align__(16) unsigned short w2T[NCLS][520];
    const int t = threadIdx.x, wv = t >> 6, lane = t & 63;
    const int q = lane >> 4, n = lane & 15;
    #pragma unroll
    for (int i = 0; i < 16; ++i) {
        const int f4 = t + 128 * i;
        const float4 v = ((const float4*)W2)[f4];
        const int k = f4 >> 2, c0 = (f4 & 3) * 4;
        w2T[c0 + 0][k] = f2bf(v.x); w2T[c0 + 1][k] = f2bf(v.y);
        w2T[c0 + 2][k] = f2bf(v.z); w2T[c0 + 3][k] = f2bf(v.w);
    }
    __syncthreads();

    const int R0 = blockIdx.x * 32;
    const int row = R0 + wv * 16 + n;
    const unsigned short* ap = hcatb + (size_t)row * NFEAT;
    f32x4 acc = {0.f, 0.f, 0.f, 0.f};
    #pragma unroll 4
    for (int k0 = 0; k0 < NFEAT; k0 += 32) {
        const bf16x8 af = *(const bf16x8*)(ap + k0 + q * 8);
        const bf16x8 bf = *(const bf16x8*)&w2T[n][k0 + q * 8];
        acc = __builtin_amdgcn_mfma_f32_16x16x32_bf16(af, bf, acc, 0, 0, 0);
    }
    uint2 w;
    w.x = pkbf(acc[0], acc[1]);
    w.y = pkbf(acc[2], acc[3]);
    // tile-major: jt = blockIdx.x, jo = wv*16 + q*4 (always < 32)
    *(uint2*)(f2t + ((size_t)blockIdx.x * 16 + n) * 32 + wv * 16 + q * 4) = w;
    const float asv = as2[n], anv = an2[n];
    #pragma unroll
    for (int i = 0; i < 4; ++i) {
        float ps = acc[i] * asv, pn = acc[i] * anv;
        #pragma unroll
        for (int off = 8; off > 0; off >>= 1) {
            ps += __shfl_xor(ps, off, 64);
            pn += __shfl_xor(pn, off, 64);
        }
        if (n == 0) {
            const int idx = R0 + wv * 16 + q * 4 + i;
            s2[idx] = ps;
            F1b[idx] = __expf(pn - BND);
            F2b[idx] = __expf(0.2f * (pn - BND));
        }
    }
}

// ---------------------------------------------------------------------------
// Layer-2 aggregation + relu + log_softmax. 1024 thr = 16 wave j-sixteenths.
// B-frags now from tile-major f2t: 1 KB/instr contiguous (R6 f1t pattern).
// ---------------------------------------------------------------------------
__global__ __launch_bounds__(1024)
void k_gat2(const unsigned short* __restrict__ f2t, const float* __restrict__ s2,
            const float* __restrict__ F1, const float* __restrict__ F2,
            const unsigned long long* __restrict__ abits, const float* __restrict__ b2,
            float* __restrict__ out)
{
    __shared__ float cmb[16][16][17];
    __shared__ float lw[16][16];
    const int t = threadIdx.x, wv = t >> 6, lane = t & 63;
    const int q = lane >> 4, n = lane & 15;
    const int R0 = blockIdx.x * 16, row = R0 + n;
    const float v = s2[row] + BND, mhat = leaky(v);
    const float E1 = __expf(v - mhat), E2 = __expf(0.2f * v - mhat);
    const unsigned long long* arow = abits + (size_t)row * 64;

    f32x4 acc = {0.f, 0.f, 0.f, 0.f};
    float lsum = 0.f;
    const int jbeg = wv * 256;
    for (int j0 = jbeg; j0 < jbeg + 256; j0 += 64) {
        const unsigned long long a64 = arow[j0 >> 6];
        #pragma unroll
        for (int ch = 0; ch < 2; ++ch) {
            const int kb = ch * 32 + q * 8;
            const float4 f1a = *(const float4*)(F1 + j0 + kb);
            const float4 f1b = *(const float4*)(F1 + j0 + kb + 4);
            const float4 f2a = *(const float4*)(F2 + j0 + kb);
            const float4 f2b = *(const float4*)(F2 + j0 + kb + 4);
            const float F1v[8] = {f1a.x, f1a.y, f1a.z, f1a.w, f1b.x, f1b.y, f1b.z, f1b.w};
            const float F2v[8] = {f2a.x, f2a.y, f2a.z, f2a.w, f2b.x, f2b.y, f2b.z, f2b.w};
            const unsigned b8 = (unsigned)(a64 >> kb) & 0xffu;
            unsigned au[4];
            #pragma unroll
            for (int jp = 0; jp < 4; ++jp) {
                float p0 = fmaxf(E1 * F1v[2*jp],   E2 * F2v[2*jp]);
                float p1 = fmaxf(E1 * F1v[2*jp+1], E2 * F2v[2*jp+1]);
                p0 = __uint_as_float(__float_as_uint(p0) & bmask(b8, 2*jp));
                p1 = __uint_as_float(__float_as_uint(p1) & bmask(b8, 2*jp+1));
                lsum += p0 + p1;
                au[jp] = pkbf(p0, p1);
            }
            const bf16x8 af = mk8(au[0], au[1], au[2], au[3]);
            const bf16x8 bf = *(const bf16x8*)(f2t + ((size_t)((j0 >> 5) + ch) * 16 + n) * 32 + q * 8);
            acc = __builtin_amdgcn_mfma_f32_16x16x32_bf16(af, bf, acc, 0, 0, 0);
        }
    }
    lsum += __shfl_xor(lsum, 16, 64);
    lsum += __shfl_xor(lsum, 32, 64);
    #pragma unroll
    for (int i = 0; i < 4; ++i) cmb[wv][q * 4 + i][n] = acc[i];
    if (q == 0) lw[wv][n] = lsum;
    __syncthreads();

    if (t < 256) {
        const int r = t >> 4, c = t & 15;
        float tot = 0.f, lt = 0.f;
        #pragma unroll
        for (int w16 = 0; w16 < 16; ++w16) { tot += cmb[w16][r][c]; lt += lw[w16][r]; }
        float val = fmaxf(tot / lt + b2[c], 0.f);
        float mx = val;
        #pragma unroll
        for (int off = 1; off < 16; off <<= 1) mx = fmaxf(mx, __shfl_xor(mx, off, 64));
        const float e = __expf(val - mx);
        float se = e;
        #pragma unroll
        for (int off = 1; off < 16; off <<= 1) se += __shfl_xor(se, off, 64);
        out[(size_t)(R0 + r) * NCLS + c] = val - mx - __logf(se);
    }
}

// ---------------------------------------------------------------------------
extern "C" void kernel_launch(void* const* d_in, const int* in_sizes, int n_in,
                              void* d_out, int out_size, void* d_ws, size_t ws_size,
                              hipStream_t stream)
{
    const float* x   = (const float*)d_in[0];
    const int*   adj = (const int*)  d_in[1];
    const float* W1  = (const float*)d_in[2];
    const float* b1  = (const float*)d_in[3];
    const float* as1 = (const float*)d_in[4];
    const float* an1 = (const float*)d_in[5];
    const float* W2  = (const float*)d_in[6];
    const float* b2  = (const float*)d_in[7];
    const float* as2 = (const float*)d_in[8];
    const float* an2 = (const float*)d_in[9];
    float* out = (float*)d_out;

    char* ws = (char*)d_ws;
    unsigned long long* abits = (unsigned long long*)(ws);            // 2 MB
    unsigned short* f1t   = (unsigned short*)(ws + (2u << 20));       // 4 MB (tile-major)
    unsigned short* hcatb = (unsigned short*)(ws + (6u << 20));       // 4 MB
    unsigned short* w1f   = (unsigned short*)(ws + (10u << 20));      // 512 KB
    char* ws2 = ws + (10u << 20) + (512u << 10);
    float* s1   = (float*)(ws2);                                      // 128 KB
    float* F1a  = (float*)(ws2 + (128u << 10));                       // 128 KB
    float* F2a  = (float*)(ws2 + (256u << 10));                       // 128 KB
    unsigned short* f2t = (unsigned short*)(ws2 + (384u << 10));      // 128 KB (tile-major)
    float* s2   = (float*)(ws2 + (512u << 10));                       // 16 KB
    float* F1b  = (float*)(ws2 + (528u << 10));                       // 16 KB
    float* F2b  = (float*)(ws2 + (544u << 10));                       // 16 KB

    k_prep  <<<dim3(NN + 64),     256, 0, stream>>>(adj, abits, W1, w1f);
    k_feats1<<<dim3(NN / 64, H1), 256, 0, stream>>>(x, w1f, as1, an1, f1t, s1, F1a, F2a);
    k_gat1  <<<dim3(NN / 32 * H1), 512, 0, stream>>>(f1t, s1, F1a, F2a, abits, b1, hcatb);
    k_feats2<<<dim3(NN / 32),     128, 0, stream>>>(hcatb, W2, as2, an2, f2t, s2, F1b, F2b);
    k_gat2  <<<dim3(NN / 16),     1024, 0, stream>>>(f2t, s2, F1b, F2b, abits, b2, out);
}